// Round 2
// baseline (3665.030 us; speedup 1.0000x reference)
//
#include <hip/hip_runtime.h>
#include <math.h>

#define Bq 8
#define Sq 1024
#define Dq 1024
#define Hq 8
#define HDq 64
#define HIDq 512
#define Pq 2048
#define EPSq 1e-6f
#define CAPq 15.0f

// ---------------- LayerNorm over D=1024, one block per row ----------------
__global__ __launch_bounds__(256) void ln_kernel(const float* __restrict__ x,
    const float* __restrict__ g, const float* __restrict__ b, float* __restrict__ y)
{
  int row = blockIdx.x;
  int tid = threadIdx.x;
  const float* xr = x + (size_t)row * Dq;
  float v[4]; float s = 0.f, s2 = 0.f;
  #pragma unroll
  for (int i = 0; i < 4; i++) { v[i] = xr[tid + 256*i]; s += v[i]; s2 += v[i]*v[i]; }
  #pragma unroll
  for (int mm = 32; mm > 0; mm >>= 1) { s += __shfl_xor(s, mm, 64); s2 += __shfl_xor(s2, mm, 64); }
  __shared__ float rs[4], rs2[4];
  int lane = tid & 63, wave = tid >> 6;
  if (lane == 0) { rs[wave] = s; rs2[wave] = s2; }
  __syncthreads();
  s  = rs[0] + rs[1] + rs[2] + rs[3];
  s2 = rs2[0] + rs2[1] + rs2[2] + rs2[3];
  float mu  = s * (1.f / Dq);
  float var = s2 * (1.f / Dq) - mu * mu;
  float r = rsqrtf(var + EPSq);
  float* yr = y + (size_t)row * Dq;
  #pragma unroll
  for (int i = 0; i < 4; i++) { int c = tid + 256*i; yr[c] = (v[i] - mu) * r * g[c] + b[c]; }
}

// ---------------- fp32 tiled GEMM: C = act((A @ W^T + bias) * scale) [+ resid] ----
// A: MxK row-major; W: NxK row-major. Tile 128x64, BK=16, 256 thr, 8x4 per thread.
__global__ __launch_bounds__(256) void gemm_kernel(const float* __restrict__ A,
    const float* __restrict__ W, const float* __restrict__ bias,
    const float* __restrict__ resid, float* __restrict__ C,
    int M, int N, int Kd, float scale, int act)
{
  __shared__ float As[16][129];
  __shared__ float Ws[16][65];
  int tid = threadIdx.x;
  int tx = tid & 15, ty = tid >> 4;   // compute roles: tx=col group, ty=row group
  int kk = tid & 15, m0 = tid >> 4;   // load roles
  int rowBase = blockIdx.y * 128;
  int colBase = blockIdx.x * 64;
  const float* Ablk = A + (size_t)rowBase * Kd;
  const float* Wblk = W + (size_t)colBase * Kd;
  float acc[8][4];
  #pragma unroll
  for (int i = 0; i < 8; i++)
    #pragma unroll
    for (int j = 0; j < 4; j++) acc[i][j] = 0.f;
  for (int k0 = 0; k0 < Kd; k0 += 16) {
    #pragma unroll
    for (int i = 0; i < 8; i++)
      As[kk][m0 + 16*i] = Ablk[(size_t)(m0 + 16*i) * Kd + k0 + kk];
    #pragma unroll
    for (int j = 0; j < 4; j++)
      Ws[kk][m0 + 16*j] = Wblk[(size_t)(m0 + 16*j) * Kd + k0 + kk];
    __syncthreads();
    #pragma unroll
    for (int kq = 0; kq < 16; kq++) {
      float a[8], w[4];
      #pragma unroll
      for (int i = 0; i < 8; i++) a[i] = As[kq][ty + 16*i];
      #pragma unroll
      for (int j = 0; j < 4; j++) w[j] = Ws[kq][tx + 16*j];
      #pragma unroll
      for (int i = 0; i < 8; i++)
        #pragma unroll
        for (int j = 0; j < 4; j++) acc[i][j] += a[i] * w[j];
    }
    __syncthreads();
  }
  #pragma unroll
  for (int i = 0; i < 8; i++) {
    int row = rowBase + ty + 16*i;
    #pragma unroll
    for (int j = 0; j < 4; j++) {
      int col = colBase + tx + 16*j;
      float val = (acc[i][j] + bias[col]) * scale;
      if (act == 1) val = 1.f / (1.f + expf(-val));
      if (resid) val += resid[(size_t)row * N + col];
      C[(size_t)row * N + col] = val;
    }
  }
}

// ---------------- causal conv over FEATURE axis (K=4) + SiLU ----------------
__global__ __launch_bounds__(256) void conv_kernel(const float* __restrict__ xt,
    const float* __restrict__ cw, const float* __restrict__ cb,
    float* __restrict__ xc, int total)
{
  int idx = blockIdx.x * 256 + threadIdx.x;
  if (idx >= total) return;
  int p = idx & (Pq - 1);
  float acc = cb[0] + cw[3] * xt[idx];
  if (p >= 1) acc += cw[2] * xt[idx - 1];
  if (p >= 2) acc += cw[1] * xt[idx - 2];
  if (p >= 3) acc += cw[0] * xt[idx - 3];
  xc[idx] = acc / (1.f + expf(-acc));   // silu
}

// ---------------- skinny i/f gate GEMM (N=8 each) + softcap ----------------
__global__ __launch_bounds__(256) void ifk_kernel(const float* __restrict__ xc,
    const float* __restrict__ Wi, const float* __restrict__ bi,
    const float* __restrict__ Wf, const float* __restrict__ bf,
    float* __restrict__ ip, float* __restrict__ fp)
{
  int row = blockIdx.x;              // b*S + t
  int lane = threadIdx.x & 63, wave = threadIdx.x >> 6;
  const float* xr = xc + (size_t)row * Pq;
  for (int oi = wave; oi < 16; oi += 4) {
    int hh = oi & 7;
    const float* Wrow = (oi < 8) ? (Wi + (size_t)hh * Pq) : (Wf + (size_t)hh * Pq);
    float s = 0.f;
    for (int j = lane; j < Pq; j += 64) s += xr[j] * Wrow[j];
    #pragma unroll
    for (int mm = 32; mm > 0; mm >>= 1) s += __shfl_xor(s, mm, 64);
    if (lane == 0) {
      float val = s + ((oi < 8) ? bi[hh] : bf[hh]);
      val = CAPq * tanhf(val / CAPq);
      if (oi < 8) ip[(size_t)row * Hq + hh] = val;
      else        fp[(size_t)row * Hq + hh] = val;
    }
  }
}

// ---------------- sequential mLSTM recurrence, one block per (b,h) ----------
// C[d][e]: d = lane (0..63), e = wave*16 + j. n/den replicated per wave.
// NOTE: q and hs may ALIAS (hs[t] written strictly after q[t] consumed; disjoint
// head slices across blocks) — no __restrict__ on them.
__global__ __launch_bounds__(256) void rec_kernel(const float* q,
    const float* __restrict__ k, const float* __restrict__ v,
    const float* __restrict__ ip, const float* __restrict__ fp,
    float* hs)
{
  int bh = blockIdx.x;
  int b = bh >> 3, hh = bh & 7;
  int tid = threadIdx.x;
  int lane = tid & 63, wave = tid >> 6;

  __shared__ float sQ[2][64], sK[2][64], sV[2][64], sIF[2][2];
  __shared__ float snum[4][64];

  float Creg[16];
  #pragma unroll
  for (int j = 0; j < 16; j++) Creg[j] = 0.f;
  float ne = 1.0f;   // n[lane], per-wave copy
  float m  = 0.0f;

  size_t base = (size_t)b * Sq * Hq * HDq + (size_t)hh * HDq;  // t stride = 512
  size_t ifb  = (size_t)b * Sq * Hq + hh;                      // t stride = 8

  float pre = 0.f;
  {
    int r = tid & 63;
    if (tid < 64)        pre = q[base + r];
    else if (tid < 128)  pre = k[base + r];
    else if (tid < 192)  pre = v[base + r];
    else if (tid == 192) pre = ip[ifb];
    else if (tid == 193) pre = fp[ifb];
  }

  int buf = 0;
  for (int t = 0; t < Sq; ++t) {
    if (tid < 64)        sQ[buf][tid]       = pre;
    else if (tid < 128)  sK[buf][tid - 64]  = pre;
    else if (tid < 192)  sV[buf][tid - 128] = pre;
    else if (tid == 192) sIF[buf][0]        = pre;
    else if (tid == 193) sIF[buf][1]        = pre;
    __syncthreads();
    // prefetch t+1 while computing t
    if (t + 1 < Sq) {
      size_t off = base + (size_t)(t + 1) * (Hq * HDq);
      int r = tid & 63;
      if (tid < 64)        pre = q[off + r];
      else if (tid < 128)  pre = k[off + r];
      else if (tid < 192)  pre = v[off + r];
      else if (tid == 192) pre = ip[ifb + (size_t)(t + 1) * Hq];
      else if (tid == 193) pre = fp[ifb + (size_t)(t + 1) * Hq];
    }
    float it = sIF[buf][0], ft = sIF[buf][1];
    float mt = fmaxf(ft + m, it);
    float ie = expf(it - mt);
    float fe = expf(ft + m - mt);
    m = mt;

    float a = ie * sV[buf][lane];      // ie * v[d]
    float numpart = 0.f;
    const float* kp = &sK[buf][wave * 16];
    const float* qp = &sQ[buf][wave * 16];
    #pragma unroll
    for (int j = 0; j < 16; j++) {
      float c2 = fe * Creg[j] + a * kp[j];
      Creg[j] = c2;
      numpart += c2 * qp[j];
    }
    ne = fe * ne + ie * sK[buf][lane];
    float dp = ne * sQ[buf][lane];
    #pragma unroll
    for (int mm = 32; mm > 0; mm >>= 1) dp += __shfl_xor(dp, mm, 64);
    snum[wave][lane] = numpart;
    __syncthreads();
    if (wave == 0) {
      float num = snum[0][lane] + snum[1][lane] + snum[2][lane] + snum[3][lane];
      float den = fmaxf(dp, 1.0f);
      hs[base + (size_t)t * (Hq * HDq) + lane] = num / den;
    }
    buf ^= 1;
  }
}

// ---------------- epilogue: h=o*hs; per-head LN; (hn+skip)*silu(r) ----------
__global__ __launch_bounds__(256) void epi_kernel(const float* __restrict__ hsv,
    const float* __restrict__ ov, const float* __restrict__ xs,
    const float* __restrict__ rt, const float* __restrict__ mg,
    const float* __restrict__ mb, float* __restrict__ pd)
{
  int tid = threadIdx.x;
  int lane = tid & 63, wave = tid >> 6;
  size_t row = (size_t)blockIdx.x * 4 + wave;   // over B*S*H
  int hh = (int)(row & 7);
  size_t idx = row * 64 + lane;
  float hv = ov[idx] * hsv[idx];
  float s = hv, s2 = hv * hv;
  #pragma unroll
  for (int mm = 32; mm > 0; mm >>= 1) { s += __shfl_xor(s, mm, 64); s2 += __shfl_xor(s2, mm, 64); }
  float mu  = s * (1.f / 64.f);
  float var = s2 * (1.f / 64.f) - mu * mu;
  float r = rsqrtf(var + EPSq);
  float hn = (hv - mu) * r * mg[hh * 64 + lane] + mb[hh * 64 + lane];
  float rv = rt[idx];
  pd[idx] = (hn + xs[idx]) * (rv / (1.f + expf(-rv)));
}

extern "C" void kernel_launch(void* const* d_in, const int* in_sizes, int n_in,
                              void* d_out, int out_size, void* d_ws, size_t ws_size,
                              hipStream_t stream)
{
  const float* x      = (const float*)d_in[0];
  const float* ln_g   = (const float*)d_in[1];
  const float* ln_b   = (const float*)d_in[2];
  const float* mh_g   = (const float*)d_in[3];
  const float* mh_b   = (const float*)d_in[4];
  const float* W_up_l = (const float*)d_in[5];
  const float* b_up_l = (const float*)d_in[6];
  const float* W_up_r = (const float*)d_in[7];
  const float* b_up_r = (const float*)d_in[8];
  const float* W_down = (const float*)d_in[9];
  const float* b_down = (const float*)d_in[10];
  const float* conv_w = (const float*)d_in[11];
  const float* conv_b = (const float*)d_in[12];
  const float* W_skip = (const float*)d_in[13];
  const float* b_skip = (const float*)d_in[14];
  const float* W_i    = (const float*)d_in[15];
  const float* b_i    = (const float*)d_in[16];
  const float* W_f    = (const float*)d_in[17];
  const float* b_f    = (const float*)d_in[18];
  const float* W_o    = (const float*)d_in[19];
  const float* b_o    = (const float*)d_in[20];
  const float* W_q    = (const float*)d_in[21];
  const float* b_q    = (const float*)d_in[22];
  const float* W_k    = (const float*)d_in[23];
  const float* b_k    = (const float*)d_in[24];
  const float* W_v    = (const float*)d_in[25];
  const float* b_v    = (const float*)d_in[26];
  float* out = (float*)d_out;

  // ---- workspace layout: peak 52M floats = 208 MiB (fits 256 MiB) ----
  float* ws = (float*)d_ws;
  const size_t MM = 1u << 20;
  if (ws_size < (size_t)52 * MM * sizeof(float)) return;  // clean fail, no OOB

  float* xn  = ws;                    // 0..8M     (dead after up GEMMs)
  float* xt  = ws + 8  * MM;          // 8..24M    (dead after conv)
  float* xc  = ws + 24 * MM;          // 24..40M
  float* rt  = ws + 40 * MM;          // 40..44M
  float* vb  = ws + 44 * MM;          // 44..48M
  float* ob  = ws + 48 * MM;          // 48..52M
  // reuse of dead regions:
  float* pd  = ws;                    // 0..4M     (xn region, after epi)
  float* ip  = ws + 4 * MM;           // 64K       (xn region, after conv)
  float* fpb = ws + 4 * MM + 65536;   // 64K
  float* xs  = ws + 8  * MM;          // 8..12M    (xt region, after conv)
  float* qb  = ws + 12 * MM;          // 12..16M
  float* kb  = ws + 16 * MM;          // 16..20M
  float* hsb = qb;                    // hs aliases qb in-place (see rec_kernel)

  const int Mrows = Bq * Sq;          // 8192

  ln_kernel<<<dim3(Mrows), dim3(256), 0, stream>>>(x, ln_g, ln_b, xn);

  gemm_kernel<<<dim3(Pq / 64, Mrows / 128), dim3(256), 0, stream>>>(
      xn, W_up_l, b_up_l, (const float*)nullptr, xt, Mrows, Pq, Dq, 1.f, 0);
  gemm_kernel<<<dim3(HIDq / 64, Mrows / 128), dim3(256), 0, stream>>>(
      xn, W_up_r, b_up_r, (const float*)nullptr, rt, Mrows, HIDq, Dq, 1.f, 0);

  // v, o read x_t -> run BEFORE conv so x_t's region can be reused after
  gemm_kernel<<<dim3(HIDq / 64, Mrows / 128), dim3(256), 0, stream>>>(
      xt, W_v, b_v, (const float*)nullptr, vb, Mrows, HIDq, Pq, 1.f, 0);
  gemm_kernel<<<dim3(HIDq / 64, Mrows / 128), dim3(256), 0, stream>>>(
      xt, W_o, b_o, (const float*)nullptr, ob, Mrows, HIDq, Pq, 1.f, 1);

  int convTotal = Mrows * Pq;
  conv_kernel<<<dim3(convTotal / 256), dim3(256), 0, stream>>>(xt, conv_w, conv_b, xc, convTotal);
  // xt dead from here on

  gemm_kernel<<<dim3(HIDq / 64, Mrows / 128), dim3(256), 0, stream>>>(
      xc, W_skip, b_skip, (const float*)nullptr, xs, Mrows, HIDq, Pq, 1.f, 0);
  gemm_kernel<<<dim3(HIDq / 64, Mrows / 128), dim3(256), 0, stream>>>(
      xc, W_q, b_q, (const float*)nullptr, qb, Mrows, HIDq, Pq, 1.f, 0);
  gemm_kernel<<<dim3(HIDq / 64, Mrows / 128), dim3(256), 0, stream>>>(
      xc, W_k, b_k, (const float*)nullptr, kb, Mrows, HIDq, Pq, 0.125f, 0);

  ifk_kernel<<<dim3(Mrows), dim3(256), 0, stream>>>(xc, W_i, b_i, W_f, b_f, ip, fpb);

  rec_kernel<<<dim3(Bq * Hq), dim3(256), 0, stream>>>(qb, kb, vb, ip, fpb, hsb);

  epi_kernel<<<dim3(Mrows * Hq / 4), dim3(256), 0, stream>>>(hsb, ob, xs, rt, mh_g, mh_b, pd);

  gemm_kernel<<<dim3(Dq / 64, Mrows / 128), dim3(256), 0, stream>>>(
      pd, W_down, b_down, x, out, Mrows, Dq, HIDq, 1.f, 0);
}

// Round 4
// 1853.749 us; speedup vs baseline: 1.9771x; 1.9771x over previous
//
#include <hip/hip_runtime.h>
#include <hip/hip_bf16.h>
#include <math.h>

#define Bq 8
#define Sq 1024
#define Dq 1024
#define Hq 8
#define HDq 64
#define HIDq 512
#define Pq 2048
#define EPSq 1e-6f
#define CAPq 15.0f

typedef __attribute__((ext_vector_type(8))) short short8;
typedef __attribute__((ext_vector_type(4))) float f32x4v;
typedef __hip_bfloat16 bf16;

__device__ inline void split2(float v, bf16& h, bf16& l) {
  h = __float2bfloat16(v);
  l = __float2bfloat16(v - __bfloat162float(h));
}

// ---------------- fp32 -> (hi,lo) bf16 split convert ----------------
__global__ __launch_bounds__(256) void cvtw_kernel(const float* __restrict__ src,
    bf16* __restrict__ hi, bf16* __restrict__ lo, int n4)
{
  int i = blockIdx.x * 256 + threadIdx.x;
  if (i >= n4) return;
  float4 v = ((const float4*)src)[i];
  bf16 h, l;
  split2(v.x, h, l); hi[i*4+0] = h; lo[i*4+0] = l;
  split2(v.y, h, l); hi[i*4+1] = h; lo[i*4+1] = l;
  split2(v.z, h, l); hi[i*4+2] = h; lo[i*4+2] = l;
  split2(v.w, h, l); hi[i*4+3] = h; lo[i*4+3] = l;
}

// ---------------- LayerNorm over D=1024 -> hi/lo bf16 out ----------------
__global__ __launch_bounds__(256) void ln_kernel(const float* __restrict__ x,
    const float* __restrict__ g, const float* __restrict__ b,
    bf16* __restrict__ yh, bf16* __restrict__ yl)
{
  int row = blockIdx.x;
  int tid = threadIdx.x;
  const float* xr = x + (size_t)row * Dq;
  float v[4]; float s = 0.f, s2 = 0.f;
  #pragma unroll
  for (int i = 0; i < 4; i++) { v[i] = xr[tid + 256*i]; s += v[i]; s2 += v[i]*v[i]; }
  #pragma unroll
  for (int mm = 32; mm > 0; mm >>= 1) { s += __shfl_xor(s, mm, 64); s2 += __shfl_xor(s2, mm, 64); }
  __shared__ float rs[4], rs2[4];
  int lane = tid & 63, wave = tid >> 6;
  if (lane == 0) { rs[wave] = s; rs2[wave] = s2; }
  __syncthreads();
  s  = rs[0] + rs[1] + rs[2] + rs[3];
  s2 = rs2[0] + rs2[1] + rs2[2] + rs2[3];
  float mu  = s * (1.f / Dq);
  float var = s2 * (1.f / Dq) - mu * mu;
  float r = rsqrtf(var + EPSq);
  #pragma unroll
  for (int i = 0; i < 4; i++) {
    int c = tid + 256*i;
    float y = (v[i] - mu) * r * g[c] + b[c];
    bf16 h, l; split2(y, h, l);
    yh[(size_t)row * Dq + c] = h;
    yl[(size_t)row * Dq + c] = l;
  }
}

// ------------- bf16x3 MFMA GEMM, 128x128 tile, BK=32, 256 thr --------------
// A, W given as hi/lo bf16 pairs (row-major, W is B^T: Ntot x K).
// acc = Ahi*Whi + Ahi*Wlo + Alo*Whi  (~fp32 precision).
// 3 column segments; block cols never straddle a segment boundary.
// Per seg: fp32 out and/or (hi,lo) bf16 out, own bias/width/scale/act.
__global__ __launch_bounds__(256) void gemm_x3(
    const bf16* __restrict__ Ahi, const bf16* __restrict__ Alo,
    const bf16* __restrict__ Whi, const bf16* __restrict__ Wlo,
    int Kd, int start1, int start2, const float* __restrict__ resid,
    const float* bias0, float* f0, bf16* h0, bf16* l0, int w0, float sc0, int a0,
    const float* bias1, float* f1, bf16* h1, bf16* l1, int w1, float sc1, int a1,
    const float* bias2, float* f2, bf16* h2, bf16* l2, int w2, float sc2, int a2)
{
  __shared__ short Ah[128 * 32];
  __shared__ short Al[128 * 32];
  __shared__ short Bh[128 * 32];
  __shared__ short Bl[128 * 32];
  int tid = threadIdx.x;
  int lane = tid & 63, wave = tid >> 6;
  int wr = wave >> 1, wc = wave & 1;            // wave tile 64x64
  int rowBase = blockIdx.y * 128;
  int colBase = blockIdx.x * 128;

  int sk  = (tid & 3) * 8;
  int sr0 = tid >> 2;          // 0..63
  int sr1 = 64 + sr0;

  const short* Ahg = (const short*)Ahi + (size_t)rowBase * Kd;
  const short* Alg = (const short*)Alo + (size_t)rowBase * Kd;
  const short* Bhg = (const short*)Whi + (size_t)colBase * Kd;
  const short* Blg = (const short*)Wlo + (size_t)colBase * Kd;

  f32x4v acc[4][4];
  #pragma unroll
  for (int i = 0; i < 4; i++)
    #pragma unroll
    for (int j = 0; j < 4; j++) acc[i][j] = (f32x4v){0.f, 0.f, 0.f, 0.f};

  int fk = (lane >> 4) * 8;
  int fr = lane & 15;

  for (int k0 = 0; k0 < Kd; k0 += 32) {
    short8 ah0 = *(const short8*)(Ahg + (size_t)sr0 * Kd + k0 + sk);
    short8 ah1 = *(const short8*)(Ahg + (size_t)sr1 * Kd + k0 + sk);
    short8 al0 = *(const short8*)(Alg + (size_t)sr0 * Kd + k0 + sk);
    short8 al1 = *(const short8*)(Alg + (size_t)sr1 * Kd + k0 + sk);
    short8 bh0 = *(const short8*)(Bhg + (size_t)sr0 * Kd + k0 + sk);
    short8 bh1 = *(const short8*)(Bhg + (size_t)sr1 * Kd + k0 + sk);
    short8 bl0 = *(const short8*)(Blg + (size_t)sr0 * Kd + k0 + sk);
    short8 bl1 = *(const short8*)(Blg + (size_t)sr1 * Kd + k0 + sk);
    __syncthreads();   // prior iteration's LDS reads done
    *(short8*)&Ah[sr0 * 32 + sk] = ah0;
    *(short8*)&Ah[sr1 * 32 + sk] = ah1;
    *(short8*)&Al[sr0 * 32 + sk] = al0;
    *(short8*)&Al[sr1 * 32 + sk] = al1;
    *(short8*)&Bh[sr0 * 32 + sk] = bh0;
    *(short8*)&Bh[sr1 * 32 + sk] = bh1;
    *(short8*)&Bl[sr0 * 32 + sk] = bl0;
    *(short8*)&Bl[sr1 * 32 + sk] = bl1;
    __syncthreads();
    short8 afh[4], afl[4], bfh[4], bfl[4];
    #pragma unroll
    for (int mi = 0; mi < 4; mi++) {
      afh[mi] = *(const short8*)&Ah[(wr * 64 + mi * 16 + fr) * 32 + fk];
      afl[mi] = *(const short8*)&Al[(wr * 64 + mi * 16 + fr) * 32 + fk];
    }
    #pragma unroll
    for (int ni = 0; ni < 4; ni++) {
      bfh[ni] = *(const short8*)&Bh[(wc * 64 + ni * 16 + fr) * 32 + fk];
      bfl[ni] = *(const short8*)&Bl[(wc * 64 + ni * 16 + fr) * 32 + fk];
    }
    #pragma unroll
    for (int mi = 0; mi < 4; mi++)
      #pragma unroll
      for (int ni = 0; ni < 4; ni++)
        acc[mi][ni] = __builtin_amdgcn_mfma_f32_16x16x32_bf16(afh[mi], bfh[ni], acc[mi][ni], 0, 0, 0);
    #pragma unroll
    for (int mi = 0; mi < 4; mi++)
      #pragma unroll
      for (int ni = 0; ni < 4; ni++)
        acc[mi][ni] = __builtin_amdgcn_mfma_f32_16x16x32_bf16(afh[mi], bfl[ni], acc[mi][ni], 0, 0, 0);
    #pragma unroll
    for (int mi = 0; mi < 4; mi++)
      #pragma unroll
      for (int ni = 0; ni < 4; ni++)
        acc[mi][ni] = __builtin_amdgcn_mfma_f32_16x16x32_bf16(afl[mi], bfh[ni], acc[mi][ni], 0, 0, 0);
  }

  // segment select (uniform per block)
  const float* bias; float* fOut; bf16* hOut; bf16* lOut; int segStart, segW; float sscale; int sact;
  if (colBase >= start2)      { bias=bias2; fOut=f2; hOut=h2; lOut=l2; segStart=start2; segW=w2; sscale=sc2; sact=a2; }
  else if (colBase >= start1) { bias=bias1; fOut=f1; hOut=h1; lOut=l1; segStart=start1; segW=w1; sscale=sc1; sact=a1; }
  else                        { bias=bias0; fOut=f0; hOut=h0; lOut=l0; segStart=0;      segW=w0; sscale=sc0; sact=a0; }

  int cr = (lane >> 4) * 4;
  int cc = lane & 15;
  #pragma unroll
  for (int mi = 0; mi < 4; mi++) {
    #pragma unroll
    for (int ni = 0; ni < 4; ni++) {
      int col  = colBase + wc * 64 + ni * 16 + cc;
      int colL = col - segStart;
      float bv = bias[colL];
      #pragma unroll
      for (int j = 0; j < 4; j++) {
        int row = rowBase + wr * 64 + mi * 16 + cr + j;
        float val = (acc[mi][ni][j] + bv) * sscale;
        if (sact) val = 1.f / (1.f + expf(-val));
        if (resid && segStart == 0) val += resid[(size_t)row * segW + colL];
        size_t oidx = (size_t)row * segW + colL;
        if (fOut) fOut[oidx] = val;
        if (hOut) {
          bf16 h, l; split2(val, h, l);
          hOut[oidx] = h; lOut[oidx] = l;
        }
      }
    }
  }
}

// ---------------- causal conv over FEATURE axis (K=4) + SiLU ----------------
__global__ __launch_bounds__(256) void conv_kernel(const bf16* __restrict__ xth,
    const bf16* __restrict__ xtl, const float* __restrict__ cw,
    const float* __restrict__ cb, bf16* __restrict__ xch, bf16* __restrict__ xcl,
    int total)
{
  int idx = blockIdx.x * 256 + threadIdx.x;
  if (idx >= total) return;
  int p = idx & (Pq - 1);
  #define XT(i) (__bfloat162float(xth[i]) + __bfloat162float(xtl[i]))
  float acc = cb[0] + cw[3] * XT(idx);
  if (p >= 1) acc += cw[2] * XT(idx - 1);
  if (p >= 2) acc += cw[1] * XT(idx - 2);
  if (p >= 3) acc += cw[0] * XT(idx - 3);
  #undef XT
  float y = acc / (1.f + expf(-acc));   // silu
  bf16 h, l; split2(y, h, l);
  xch[idx] = h; xcl[idx] = l;
}

// ---------------- skinny i/f gate GEMM (N=8 each) + softcap ----------------
__global__ __launch_bounds__(256) void ifk_kernel(const bf16* __restrict__ xch,
    const bf16* __restrict__ xcl,
    const float* __restrict__ Wi, const float* __restrict__ bi,
    const float* __restrict__ Wf, const float* __restrict__ bf_,
    float* __restrict__ ip, float* __restrict__ fp)
{
  int row = blockIdx.x;              // b*S + t
  int lane = threadIdx.x & 63, wave = threadIdx.x >> 6;
  size_t rb = (size_t)row * Pq;
  for (int oi = wave; oi < 16; oi += 4) {
    int hh = oi & 7;
    const float* Wrow = (oi < 8) ? (Wi + (size_t)hh * Pq) : (Wf + (size_t)hh * Pq);
    float s = 0.f;
    for (int j = lane; j < Pq; j += 64)
      s += (__bfloat162float(xch[rb + j]) + __bfloat162float(xcl[rb + j])) * Wrow[j];
    #pragma unroll
    for (int mm = 32; mm > 0; mm >>= 1) s += __shfl_xor(s, mm, 64);
    if (lane == 0) {
      float val = s + ((oi < 8) ? bi[hh] : bf_[hh]);
      val = CAPq * tanhf(val / CAPq);
      if (oi < 8) ip[(size_t)row * Hq + hh] = val;
      else        fp[(size_t)row * Hq + hh] = val;
    }
  }
}

// ---------------- sequential mLSTM recurrence, one block per (b,h) ----------
// q and hs may ALIAS (hs[t] written strictly after q[t] consumed).
__global__ __launch_bounds__(256) void rec_kernel(const float* q,
    const float* __restrict__ k, const float* __restrict__ v,
    const float* __restrict__ ip, const float* __restrict__ fp,
    float* hs)
{
  int bh = blockIdx.x;
  int b = bh >> 3, hh = bh & 7;
  int tid = threadIdx.x;
  int lane = tid & 63, wave = tid >> 6;

  __shared__ float sQ[2][64], sK[2][64], sV[2][64], sIF[2][2];
  __shared__ float snum[4][64];

  float Creg[16];
  #pragma unroll
  for (int j = 0; j < 16; j++) Creg[j] = 0.f;
  float ne = 1.0f;
  float m  = 0.0f;

  size_t base = (size_t)b * Sq * Hq * HDq + (size_t)hh * HDq;
  size_t ifb  = (size_t)b * Sq * Hq + hh;

  float pre = 0.f;
  {
    int r = tid & 63;
    if (tid < 64)        pre = q[base + r];
    else if (tid < 128)  pre = k[base + r];
    else if (tid < 192)  pre = v[base + r];
    else if (tid == 192) pre = ip[ifb];
    else if (tid == 193) pre = fp[ifb];
  }

  int buf = 0;
  for (int t = 0; t < Sq; ++t) {
    if (tid < 64)        sQ[buf][tid]       = pre;
    else if (tid < 128)  sK[buf][tid - 64]  = pre;
    else if (tid < 192)  sV[buf][tid - 128] = pre;
    else if (tid == 192) sIF[buf][0]        = pre;
    else if (tid == 193) sIF[buf][1]        = pre;
    __syncthreads();
    if (t + 1 < Sq) {
      size_t off = base + (size_t)(t + 1) * (Hq * HDq);
      int r = tid & 63;
      if (tid < 64)        pre = q[off + r];
      else if (tid < 128)  pre = k[off + r];
      else if (tid < 192)  pre = v[off + r];
      else if (tid == 192) pre = ip[ifb + (size_t)(t + 1) * Hq];
      else if (tid == 193) pre = fp[ifb + (size_t)(t + 1) * Hq];
    }
    float it = sIF[buf][0], ft = sIF[buf][1];
    float mt = fmaxf(ft + m, it);
    float ie = expf(it - mt);
    float fe = expf(ft + m - mt);
    m = mt;

    float a = ie * sV[buf][lane];
    float numpart = 0.f;
    const float* kp = &sK[buf][wave * 16];
    const float* qp = &sQ[buf][wave * 16];
    #pragma unroll
    for (int j = 0; j < 16; j++) {
      float c2 = fe * Creg[j] + a * kp[j];
      Creg[j] = c2;
      numpart += c2 * qp[j];
    }
    ne = fe * ne + ie * sK[buf][lane];
    float dp = ne * sQ[buf][lane];
    #pragma unroll
    for (int mm = 32; mm > 0; mm >>= 1) dp += __shfl_xor(dp, mm, 64);
    snum[wave][lane] = numpart;
    __syncthreads();
    if (wave == 0) {
      float num = snum[0][lane] + snum[1][lane] + snum[2][lane] + snum[3][lane];
      float den = fmaxf(dp, 1.0f);
      hs[base + (size_t)t * (Hq * HDq) + lane] = num / den;
    }
    buf ^= 1;
  }
}

// ------ epilogue: h=o*hs; per-head LN; (hn+skip)*silu(r) -> hi/lo bf16 ------
__global__ __launch_bounds__(256) void epi_kernel(const float* __restrict__ hsv,
    const float* __restrict__ ov, const float* __restrict__ xs,
    const float* __restrict__ rt, const float* __restrict__ mg,
    const float* __restrict__ mb, bf16* __restrict__ pdh, bf16* __restrict__ pdl)
{
  int tid = threadIdx.x;
  int lane = tid & 63, wave = tid >> 6;
  size_t row = (size_t)blockIdx.x * 4 + wave;   // over B*S*H
  int hh = (int)(row & 7);
  size_t idx = row * 64 + lane;
  float hv = ov[idx] * hsv[idx];
  float s = hv, s2 = hv * hv;
  #pragma unroll
  for (int mm = 32; mm > 0; mm >>= 1) { s += __shfl_xor(s, mm, 64); s2 += __shfl_xor(s2, mm, 64); }
  float mu  = s * (1.f / 64.f);
  float var = s2 * (1.f / 64.f) - mu * mu;
  float r = rsqrtf(var + EPSq);
  float hn = (hv - mu) * r * mg[hh * 64 + lane] + mb[hh * 64 + lane];
  float rv = rt[idx];
  float y = (hn + xs[idx]) * (rv / (1.f + expf(-rv)));
  bf16 h, l; split2(y, h, l);
  pdh[idx] = h; pdl[idx] = l;
}

extern "C" void kernel_launch(void* const* d_in, const int* in_sizes, int n_in,
                              void* d_out, int out_size, void* d_ws, size_t ws_size,
                              hipStream_t stream)
{
  const float* x      = (const float*)d_in[0];
  const float* ln_g   = (const float*)d_in[1];
  const float* ln_b   = (const float*)d_in[2];
  const float* mh_g   = (const float*)d_in[3];
  const float* mh_b   = (const float*)d_in[4];
  const float* W_up_l = (const float*)d_in[5];
  const float* b_up_l = (const float*)d_in[6];
  const float* W_up_r = (const float*)d_in[7];
  const float* b_up_r = (const float*)d_in[8];
  const float* W_down = (const float*)d_in[9];
  const float* b_down = (const float*)d_in[10];
  const float* conv_w = (const float*)d_in[11];
  const float* conv_b = (const float*)d_in[12];
  const float* W_skip = (const float*)d_in[13];
  const float* b_skip = (const float*)d_in[14];
  const float* W_i    = (const float*)d_in[15];
  const float* b_i    = (const float*)d_in[16];
  const float* W_f    = (const float*)d_in[17];
  const float* b_f    = (const float*)d_in[18];
  const float* W_o    = (const float*)d_in[19];
  const float* b_o    = (const float*)d_in[20];
  const float* W_q    = (const float*)d_in[21];
  const float* b_q    = (const float*)d_in[22];
  const float* W_k    = (const float*)d_in[23];
  const float* b_k    = (const float*)d_in[24];
  const float* W_v    = (const float*)d_in[25];
  const float* b_v    = (const float*)d_in[26];
  float* out = (float*)d_out;

  const size_t MB = 1u << 20;
  if (ws_size < 193 * MB) return;   // need 192.5 MiB (round-2 proved >=208 MiB)

  char* base = (char*)d_ws;
  // weight hi/lo arenas (8M elements each): up@0 (2.5M), vo@2.5M (2M),
  // sqk@4.5M (3M), dn@7.5M (0.5M)
  bf16* whi = (bf16*)base;             // 0..16 MB
  bf16* wlo = (bf16*)(base + 16*MB);   // 16..32 MB
  // activations (hi/lo pairs, 4 B/el total — same footprint as fp32)
  bf16* xnh = (bf16*)(base + 32*MB);   // 32..48
  bf16* xnl = (bf16*)(base + 48*MB);   // 48..64   (xn dead after up GEMM)
  bf16* xth = (bf16*)(base + 64*MB);   // 64..96
  bf16* xtl = (bf16*)(base + 96*MB);   // 96..128  (xt dead after conv)
  bf16* xch = (bf16*)(base + 128*MB);  // 128..160
  bf16* xcl = (bf16*)(base + 160*MB);  // 160..192
  // reuse of dead regions:
  float* vb  = (float*)(base + 32*MB); // xn region
  float* ob  = (float*)(base + 48*MB);
  float* xs  = (float*)(base + 64*MB); // xt region
  float* qb  = (float*)(base + 80*MB);
  float* kb  = (float*)(base + 96*MB);
  bf16*  pdh = (bf16*)(base + 112*MB);
  bf16*  pdl = (bf16*)(base + 120*MB);
  float* ip  = (float*)(base + 192*MB);
  float* fpb = (float*)(base + 192*MB + 256*1024);
  float* rt  = out;                    // d_out[0..16MB] as scratch; down GEMM
                                       // overwrites all of d_out afterwards
  float* hsb = qb;                     // hs aliases qb (see rec_kernel)

  const int Mrows = Bq * Sq;   // 8192
  const int BIG = 1 << 30;

  // ---- weight split into packed hi/lo arenas ----
  auto cvtw = [&](const float* s, size_t off, int n) {
    cvtw_kernel<<<dim3((n/4 + 255)/256), dim3(256), 0, stream>>>(s, whi + off, wlo + off, n/4);
  };
  cvtw(W_up_l, 0,           2048*1024);
  cvtw(W_up_r, 2048*1024,   512*1024);
  cvtw(W_v,    2621440,           512*2048);
  cvtw(W_o,    2621440 + 1048576, 512*2048);
  cvtw(W_skip, 4718592,             512*2048);
  cvtw(W_q,    4718592 + 1048576,   512*2048);
  cvtw(W_k,    4718592 + 2*1048576, 512*2048);
  cvtw(W_down, 7864320,   1024*512);

  ln_kernel<<<dim3(Mrows), dim3(256), 0, stream>>>(x, ln_g, ln_b, xnh, xnl);

  // up-fused: N=2560, K=1024. seg0 [0,2048)->xt hi/lo; seg1 [2048,2560)->rt f32
  gemm_x3<<<dim3(20, 64), dim3(256), 0, stream>>>(
      xnh, xnl, whi, wlo, 1024, 2048, BIG, nullptr,
      b_up_l, nullptr, xth, xtl, 2048, 1.f, 0,
      b_up_r, rt, nullptr, nullptr, 512, 1.f, 0,
      nullptr, nullptr, nullptr, nullptr, 1, 1.f, 0);

  // vo-fused: N=1024, K=2048. seg0 -> vb f32; seg1 -> ob f32 (sigmoid)
  gemm_x3<<<dim3(8, 64), dim3(256), 0, stream>>>(
      xth, xtl, whi + 2621440, wlo + 2621440, 2048, 512, BIG, nullptr,
      b_v, vb, nullptr, nullptr, 512, 1.f, 0,
      b_o, ob, nullptr, nullptr, 512, 1.f, 1,
      nullptr, nullptr, nullptr, nullptr, 1, 1.f, 0);

  int convTotal = Mrows * Pq;
  conv_kernel<<<dim3(convTotal / 256), dim3(256), 0, stream>>>(
      xth, xtl, conv_w, conv_b, xch, xcl, convTotal);
  // xt dead from here on

  // sqk-fused: N=1536, K=2048. seg0->xs; seg1->qb; seg2->kb (scale 1/8)
  gemm_x3<<<dim3(12, 64), dim3(256), 0, stream>>>(
      xch, xcl, whi + 4718592, wlo + 4718592, 2048, 512, 1024, nullptr,
      b_skip, xs, nullptr, nullptr, 512, 1.f, 0,
      b_q, qb, nullptr, nullptr, 512, 1.f, 0,
      b_k, kb, nullptr, nullptr, 512, 0.125f, 0);

  ifk_kernel<<<dim3(Mrows), dim3(256), 0, stream>>>(
      xch, xcl, W_i, b_i, W_f, b_f, ip, fpb);

  rec_kernel<<<dim3(Bq * Hq), dim3(256), 0, stream>>>(qb, kb, vb, ip, fpb, hsb);

  epi_kernel<<<dim3(Mrows * Hq / 4), dim3(256), 0, stream>>>(
      hsb, ob, xs, rt, mh_g, mh_b, pdh, pdl);

  // down: N=1024, K=512, residual x, fp32 out (overwrites rt scratch region)
  gemm_x3<<<dim3(8, 64), dim3(256), 0, stream>>>(
      pdh, pdl, whi + 7864320, wlo + 7864320, 512, BIG, BIG, x,
      b_down, out, nullptr, nullptr, 1024, 1.f, 0,
      nullptr, nullptr, nullptr, nullptr, 1, 1.f, 0,
      nullptr, nullptr, nullptr, nullptr, 1, 1.f, 0);
}

// Round 5
// 1050.130 us; speedup vs baseline: 3.4901x; 1.7653x over previous
//
#include <hip/hip_runtime.h>
#include <hip/hip_bf16.h>
#include <math.h>

#define Bq 8
#define Sq 1024
#define Dq 1024
#define Hq 8
#define HDq 64
#define HIDq 512
#define Pq 2048
#define EPSq 1e-6f
#define CAPq 15.0f
#define NCq 16    // chunks per sequence
#define CLq 64    // chunk length

typedef __attribute__((ext_vector_type(8))) short short8;
typedef __attribute__((ext_vector_type(4))) float f32x4v;
typedef __hip_bfloat16 bf16;

__device__ inline void split2(float v, bf16& h, bf16& l) {
  h = __float2bfloat16(v);
  l = __float2bfloat16(v - __bfloat162float(h));
}

// ---------------- fp32 -> (hi,lo) bf16 split convert ----------------
__global__ __launch_bounds__(256) void cvtw_kernel(const float* __restrict__ src,
    bf16* __restrict__ hi, bf16* __restrict__ lo, int n4)
{
  int i = blockIdx.x * 256 + threadIdx.x;
  if (i >= n4) return;
  float4 v = ((const float4*)src)[i];
  bf16 h, l;
  split2(v.x, h, l); hi[i*4+0] = h; lo[i*4+0] = l;
  split2(v.y, h, l); hi[i*4+1] = h; lo[i*4+1] = l;
  split2(v.z, h, l); hi[i*4+2] = h; lo[i*4+2] = l;
  split2(v.w, h, l); hi[i*4+3] = h; lo[i*4+3] = l;
}

// ---------------- LayerNorm over D=1024 -> hi/lo bf16 out ----------------
__global__ __launch_bounds__(256) void ln_kernel(const float* __restrict__ x,
    const float* __restrict__ g, const float* __restrict__ b,
    bf16* __restrict__ yh, bf16* __restrict__ yl)
{
  int row = blockIdx.x;
  int tid = threadIdx.x;
  const float* xr = x + (size_t)row * Dq;
  float v[4]; float s = 0.f, s2 = 0.f;
  #pragma unroll
  for (int i = 0; i < 4; i++) { v[i] = xr[tid + 256*i]; s += v[i]; s2 += v[i]*v[i]; }
  #pragma unroll
  for (int mm = 32; mm > 0; mm >>= 1) { s += __shfl_xor(s, mm, 64); s2 += __shfl_xor(s2, mm, 64); }
  __shared__ float rs[4], rs2[4];
  int lane = tid & 63, wave = tid >> 6;
  if (lane == 0) { rs[wave] = s; rs2[wave] = s2; }
  __syncthreads();
  s  = rs[0] + rs[1] + rs[2] + rs[3];
  s2 = rs2[0] + rs2[1] + rs2[2] + rs2[3];
  float mu  = s * (1.f / Dq);
  float var = s2 * (1.f / Dq) - mu * mu;
  float r = rsqrtf(var + EPSq);
  #pragma unroll
  for (int i = 0; i < 4; i++) {
    int c = tid + 256*i;
    float y = (v[i] - mu) * r * g[c] + b[c];
    bf16 h, l; split2(y, h, l);
    yh[(size_t)row * Dq + c] = h;
    yl[(size_t)row * Dq + c] = l;
  }
}

// ------------- bf16x3 MFMA GEMM, 128x128 tile, BK=32, 256 thr --------------
__global__ __launch_bounds__(256) void gemm_x3(
    const bf16* __restrict__ Ahi, const bf16* __restrict__ Alo,
    const bf16* __restrict__ Whi, const bf16* __restrict__ Wlo,
    int Kd, int start1, int start2, const float* __restrict__ resid,
    const float* bias0, float* f0, bf16* h0, bf16* l0, int w0, float sc0, int a0,
    const float* bias1, float* f1, bf16* h1, bf16* l1, int w1, float sc1, int a1,
    const float* bias2, float* f2, bf16* h2, bf16* l2, int w2, float sc2, int a2)
{
  __shared__ short Ah[128 * 32];
  __shared__ short Al[128 * 32];
  __shared__ short Bh[128 * 32];
  __shared__ short Bl[128 * 32];
  int tid = threadIdx.x;
  int lane = tid & 63, wave = tid >> 6;
  int wr = wave >> 1, wc = wave & 1;            // wave tile 64x64
  int rowBase = blockIdx.y * 128;
  int colBase = blockIdx.x * 128;

  int sk  = (tid & 3) * 8;
  int sr0 = tid >> 2;          // 0..63
  int sr1 = 64 + sr0;

  const short* Ahg = (const short*)Ahi + (size_t)rowBase * Kd;
  const short* Alg = (const short*)Alo + (size_t)rowBase * Kd;
  const short* Bhg = (const short*)Whi + (size_t)colBase * Kd;
  const short* Blg = (const short*)Wlo + (size_t)colBase * Kd;

  f32x4v acc[4][4];
  #pragma unroll
  for (int i = 0; i < 4; i++)
    #pragma unroll
    for (int j = 0; j < 4; j++) acc[i][j] = (f32x4v){0.f, 0.f, 0.f, 0.f};

  int fk = (lane >> 4) * 8;
  int fr = lane & 15;

  for (int k0 = 0; k0 < Kd; k0 += 32) {
    short8 ah0 = *(const short8*)(Ahg + (size_t)sr0 * Kd + k0 + sk);
    short8 ah1 = *(const short8*)(Ahg + (size_t)sr1 * Kd + k0 + sk);
    short8 al0 = *(const short8*)(Alg + (size_t)sr0 * Kd + k0 + sk);
    short8 al1 = *(const short8*)(Alg + (size_t)sr1 * Kd + k0 + sk);
    short8 bh0 = *(const short8*)(Bhg + (size_t)sr0 * Kd + k0 + sk);
    short8 bh1 = *(const short8*)(Bhg + (size_t)sr1 * Kd + k0 + sk);
    short8 bl0 = *(const short8*)(Blg + (size_t)sr0 * Kd + k0 + sk);
    short8 bl1 = *(const short8*)(Blg + (size_t)sr1 * Kd + k0 + sk);
    __syncthreads();
    *(short8*)&Ah[sr0 * 32 + sk] = ah0;
    *(short8*)&Ah[sr1 * 32 + sk] = ah1;
    *(short8*)&Al[sr0 * 32 + sk] = al0;
    *(short8*)&Al[sr1 * 32 + sk] = al1;
    *(short8*)&Bh[sr0 * 32 + sk] = bh0;
    *(short8*)&Bh[sr1 * 32 + sk] = bh1;
    *(short8*)&Bl[sr0 * 32 + sk] = bl0;
    *(short8*)&Bl[sr1 * 32 + sk] = bl1;
    __syncthreads();
    short8 afh[4], afl[4], bfh[4], bfl[4];
    #pragma unroll
    for (int mi = 0; mi < 4; mi++) {
      afh[mi] = *(const short8*)&Ah[(wr * 64 + mi * 16 + fr) * 32 + fk];
      afl[mi] = *(const short8*)&Al[(wr * 64 + mi * 16 + fr) * 32 + fk];
    }
    #pragma unroll
    for (int ni = 0; ni < 4; ni++) {
      bfh[ni] = *(const short8*)&Bh[(wc * 64 + ni * 16 + fr) * 32 + fk];
      bfl[ni] = *(const short8*)&Bl[(wc * 64 + ni * 16 + fr) * 32 + fk];
    }
    #pragma unroll
    for (int mi = 0; mi < 4; mi++)
      #pragma unroll
      for (int ni = 0; ni < 4; ni++)
        acc[mi][ni] = __builtin_amdgcn_mfma_f32_16x16x32_bf16(afh[mi], bfh[ni], acc[mi][ni], 0, 0, 0);
    #pragma unroll
    for (int mi = 0; mi < 4; mi++)
      #pragma unroll
      for (int ni = 0; ni < 4; ni++)
        acc[mi][ni] = __builtin_amdgcn_mfma_f32_16x16x32_bf16(afh[mi], bfl[ni], acc[mi][ni], 0, 0, 0);
    #pragma unroll
    for (int mi = 0; mi < 4; mi++)
      #pragma unroll
      for (int ni = 0; ni < 4; ni++)
        acc[mi][ni] = __builtin_amdgcn_mfma_f32_16x16x32_bf16(afl[mi], bfh[ni], acc[mi][ni], 0, 0, 0);
  }

  const float* bias; float* fOut; bf16* hOut; bf16* lOut; int segStart, segW; float sscale; int sact;
  if (colBase >= start2)      { bias=bias2; fOut=f2; hOut=h2; lOut=l2; segStart=start2; segW=w2; sscale=sc2; sact=a2; }
  else if (colBase >= start1) { bias=bias1; fOut=f1; hOut=h1; lOut=l1; segStart=start1; segW=w1; sscale=sc1; sact=a1; }
  else                        { bias=bias0; fOut=f0; hOut=h0; lOut=l0; segStart=0;      segW=w0; sscale=sc0; sact=a0; }

  int cr = (lane >> 4) * 4;
  int cc = lane & 15;
  #pragma unroll
  for (int mi = 0; mi < 4; mi++) {
    #pragma unroll
    for (int ni = 0; ni < 4; ni++) {
      int col  = colBase + wc * 64 + ni * 16 + cc;
      int colL = col - segStart;
      float bv = bias[colL];
      #pragma unroll
      for (int j = 0; j < 4; j++) {
        int row = rowBase + wr * 64 + mi * 16 + cr + j;
        float val = (acc[mi][ni][j] + bv) * sscale;
        if (sact) val = 1.f / (1.f + expf(-val));
        if (resid && segStart == 0) val += resid[(size_t)row * segW + colL];
        size_t oidx = (size_t)row * segW + colL;
        if (fOut) fOut[oidx] = val;
        if (hOut) {
          bf16 h, l; split2(val, h, l);
          hOut[oidx] = h; lOut[oidx] = l;
        }
      }
    }
  }
}

// ---------------- causal conv over FEATURE axis (K=4) + SiLU ----------------
__global__ __launch_bounds__(256) void conv_kernel(const bf16* __restrict__ xth,
    const bf16* __restrict__ xtl, const float* __restrict__ cw,
    const float* __restrict__ cb, bf16* __restrict__ xch, bf16* __restrict__ xcl,
    int total)
{
  int idx = blockIdx.x * 256 + threadIdx.x;
  if (idx >= total) return;
  int p = idx & (Pq - 1);
  #define XT(i) (__bfloat162float(xth[i]) + __bfloat162float(xtl[i]))
  float acc = cb[0] + cw[3] * XT(idx);
  if (p >= 1) acc += cw[2] * XT(idx - 1);
  if (p >= 2) acc += cw[1] * XT(idx - 2);
  if (p >= 3) acc += cw[0] * XT(idx - 3);
  #undef XT
  float y = acc / (1.f + expf(-acc));   // silu
  bf16 h, l; split2(y, h, l);
  xch[idx] = h; xcl[idx] = l;
}

// ---------------- skinny i/f gate GEMM (N=8 each) + softcap ----------------
__global__ __launch_bounds__(256) void ifk_kernel(const bf16* __restrict__ xch,
    const bf16* __restrict__ xcl,
    const float* __restrict__ Wi, const float* __restrict__ bi,
    const float* __restrict__ Wf, const float* __restrict__ bf_,
    float* __restrict__ ip, float* __restrict__ fp)
{
  int row = blockIdx.x;              // b*S + t
  int lane = threadIdx.x & 63, wave = threadIdx.x >> 6;
  size_t rb = (size_t)row * Pq;
  for (int oi = wave; oi < 16; oi += 4) {
    int hh = oi & 7;
    const float* Wrow = (oi < 8) ? (Wi + (size_t)hh * Pq) : (Wf + (size_t)hh * Pq);
    float s = 0.f;
    for (int j = lane; j < Pq; j += 64)
      s += (__bfloat162float(xch[rb + j]) + __bfloat162float(xcl[rb + j])) * Wrow[j];
    #pragma unroll
    for (int mm = 32; mm > 0; mm >>= 1) s += __shfl_xor(s, mm, 64);
    if (lane == 0) {
      float val = s + ((oi < 8) ? bi[hh] : bf_[hh]);
      val = CAPq * tanhf(val / CAPq);
      if (oi < 8) ip[(size_t)row * Hq + hh] = val;
      else        fp[(size_t)row * Hq + hh] = val;
    }
  }
}

// ===== chunkwise-parallel mLSTM recurrence =====
// b_s = i_s - cumF_s (chunk-local); m_t = cumF_t + Mrun_t,
// Mrun_t = max(m_in, cummax_{s<=t} b_s); intra weight exp(b_s - Mrun_t);
// carry-in weight exp(m_in - Mrun_t). All exponents <= 0.

// --- A: per-chunk scans + KV summary (grid: B*H*NC) ---
__global__ __launch_bounds__(256) void chunkA_kernel(const float* __restrict__ k,
    const float* __restrict__ v, const float* __restrict__ ip,
    const float* __restrict__ fp, float* __restrict__ bg,
    float* __restrict__ FcMc, float* __restrict__ kvg, float* __restrict__ ksumg)
{
  int blk = blockIdx.x;   // bh*NC + c
  int bh = blk >> 4, c = blk & 15;
  int b = bh >> 3, hh = bh & 7;
  int tid = threadIdx.x, lane = tid & 63, wave = tid >> 6;

  __shared__ float sK[64][64], sV[64][64], sW[64];

  size_t base = (size_t)b * Sq * 512 + (size_t)hh * 64 + (size_t)c * CLq * 512;
  #pragma unroll 4
  for (int i = 0; i < 16; i++) {
    int t = wave * 16 + i;
    sK[t][lane] = k[base + (size_t)t * 512 + lane];
    sV[t][lane] = v[base + (size_t)t * 512 + lane];
  }
  if (tid < 64) {
    size_t ifb = ((size_t)b * Sq + c * CLq + tid) * Hq + hh;
    float fv = fp[ifb], iv = ip[ifb];
    float cf = fv;                       // inclusive sum scan of f
    #pragma unroll
    for (int off = 1; off < 64; off <<= 1) {
      float t2 = __shfl_up(cf, off, 64);
      if (lane >= off) cf += t2;
    }
    float bs = iv - cf;
    float mx = bs;                       // inclusive max scan
    #pragma unroll
    for (int off = 1; off < 64; off <<= 1) {
      float t2 = __shfl_up(mx, off, 64);
      if (lane >= off) mx = fmaxf(mx, t2);
    }
    float Mc = __shfl(mx, 63, 64);
    bg[(size_t)blk * 64 + tid] = bs;
    sW[tid] = expf(bs - Mc);
    if (tid == 63) { FcMc[blk*2] = cf; FcMc[blk*2+1] = Mc; }
  }
  __syncthreads();
  // kv[d][e] = sum_s w_s * v_s[d] * k_s[e];  d=lane, e=wave*16+j
  float acc[16];
  #pragma unroll
  for (int j = 0; j < 16; j++) acc[j] = 0.f;
  for (int s = 0; s < 64; s++) {
    float wv = sW[s] * sV[s][lane];
    #pragma unroll
    for (int j = 0; j < 16; j++) acc[j] += wv * sK[s][wave*16+j];
  }
  float* kvp = kvg + (size_t)blk * 4096 + lane * 64 + wave * 16;
  #pragma unroll
  for (int j = 0; j < 16; j++) kvp[j] = acc[j];
  if (tid < 64) {
    float a = 0.f;
    for (int s = 0; s < 64; s++) a += sW[s] * sK[s][tid];
    ksumg[(size_t)blk * 64 + tid] = a;
  }
}

// --- B: boundary-state propagation, 16 sequential chunk steps (grid: B*H) ---
__global__ __launch_bounds__(256) void chunkB_kernel(const float* __restrict__ kvg,
    const float* __restrict__ ksumg, const float* __restrict__ FcMc,
    float* __restrict__ boundC, float* __restrict__ boundN, float* __restrict__ boundM)
{
  int bh = blockIdx.x;
  int tid = threadIdx.x, lane = tid & 63, wave = tid >> 6;
  float C[16];
  #pragma unroll
  for (int j = 0; j < 16; j++) C[j] = 0.f;
  float ne = 1.0f, m = 0.f;              // n0 = ones, m0 = 0
  for (int c = 0; c < NCq; c++) {
    size_t blk = (size_t)bh * NCq + c;
    float* bC = boundC + blk * 4096 + lane * 64 + wave * 16;
    #pragma unroll
    for (int j = 0; j < 16; j++) bC[j] = C[j];
    if (wave == 0) boundN[blk * 64 + lane] = ne;
    if (tid == 0)  boundM[blk] = m;
    float Fc = FcMc[blk * 2], Mc = FcMc[blk * 2 + 1];
    float mm = fmaxf(m, Mc);
    float a1 = expf(m - mm), a2 = expf(Mc - mm);
    const float* kv = kvg + blk * 4096 + lane * 64 + wave * 16;
    #pragma unroll
    for (int j = 0; j < 16; j++) C[j] = a1 * C[j] + a2 * kv[j];
    ne = a1 * ne + a2 * ksumg[blk * 64 + lane];
    m = Fc + mm;
  }
}

// --- C: intra-chunk parallel attention (grid: B*H*NC). q/hs may ALIAS. ---
__global__ __launch_bounds__(256) void chunkC_kernel(const float* q,
    const float* __restrict__ k, const float* __restrict__ v,
    const float* __restrict__ bg, const float* __restrict__ boundC,
    const float* __restrict__ boundN, const float* __restrict__ boundM,
    float* hs)
{
  int blk = blockIdx.x;   // bh*NC + c
  int bh = blk >> 4, c = blk & 15;
  int b = bh >> 3, hh = bh & 7;
  int tid = threadIdx.x, lane = tid & 63, wave = tid >> 6;

  __shared__ float sQ[64][65], sKV[64][65], sS[64][65];
  __shared__ float sB[64], sMr[64], sNin[64];

  size_t base = (size_t)b * Sq * 512 + (size_t)hh * 64 + (size_t)c * CLq * 512;
  #pragma unroll 4
  for (int i = 0; i < 16; i++) {
    int t = wave * 16 + i;
    sQ[t][lane]  = q[base + (size_t)t * 512 + lane];
    sKV[t][lane] = k[base + (size_t)t * 512 + lane];
  }
  float m_in = boundM[blk];
  if (tid < 64) {
    float bs = bg[(size_t)blk * 64 + tid];
    float mx = bs;
    #pragma unroll
    for (int off = 1; off < 64; off <<= 1) {
      float t2 = __shfl_up(mx, off, 64);
      if (lane >= off) mx = fmaxf(mx, t2);
    }
    sB[tid]   = bs;
    sMr[tid]  = fmaxf(m_in, mx);
    sNin[tid] = boundN[(size_t)blk * 64 + tid];
  }
  __syncthreads();

  // S: thread (t=lane, s in wave*16..+16): raw dot then apply weight
  {
    int t = lane;
    float acc[16];
    #pragma unroll
    for (int j = 0; j < 16; j++) acc[j] = 0.f;
    for (int d = 0; d < 64; d++) {
      float qv = sQ[t][d];
      #pragma unroll
      for (int j = 0; j < 16; j++) acc[j] += qv * sKV[wave*16+j][d];
    }
    float Mr = sMr[t];
    #pragma unroll
    for (int j = 0; j < 16; j++) {
      int s = wave * 16 + j;
      float w = (s <= t) ? expf(sB[s] - Mr) : 0.f;
      sS[t][s] = w * acc[j];
    }
  }
  __syncthreads();
  #pragma unroll 4
  for (int i = 0; i < 16; i++) {       // restage v over k
    int t = wave * 16 + i;
    sKV[t][lane] = v[base + (size_t)t * 512 + lane];
  }
  __syncthreads();

  // output: thread (t=lane, d in wave*16..+16)
  {
    int t = lane;
    float Mr = sMr[t];
    float bfac = expf(m_in - Mr);
    float den = 0.f;
    for (int d = 0; d < 64; d++) den += sNin[d] * sQ[t][d];
    den *= bfac;
    float num[16];
    #pragma unroll
    for (int j = 0; j < 16; j++) num[j] = 0.f;
    const float* Crow = boundC + (size_t)blk * 4096;
    for (int e = 0; e < 64; e++) {
      float qv = sQ[t][e];
      #pragma unroll
      for (int j = 0; j < 16; j++)
        num[j] += Crow[(size_t)(wave*16+j) * 64 + e] * qv;
    }
    #pragma unroll
    for (int j = 0; j < 16; j++) num[j] *= bfac;
    for (int s = 0; s < 64; s++) {
      float ws = sS[t][s];
      den += ws;
      #pragma unroll
      for (int j = 0; j < 16; j++) num[j] += ws * sKV[s][wave*16+j];
    }
    den = fmaxf(den, 1.0f);
    float o[16];
    #pragma unroll
    for (int j = 0; j < 16; j++) o[j] = num[j] / den;
    float* hp = hs + base + (size_t)t * 512 + wave * 16;
    #pragma unroll
    for (int j4 = 0; j4 < 4; j4++)
      ((float4*)hp)[j4] = ((float4*)o)[j4];
  }
}

// ------ epilogue: h=o*hs; per-head LN; (hn+skip)*silu(r) -> hi/lo bf16 ------
__global__ __launch_bounds__(256) void epi_kernel(const float* __restrict__ hsv,
    const float* __restrict__ ov, const float* __restrict__ xs,
    const float* __restrict__ rt, const float* __restrict__ mg,
    const float* __restrict__ mb, bf16* __restrict__ pdh, bf16* __restrict__ pdl)
{
  int tid = threadIdx.x;
  int lane = tid & 63, wave = tid >> 6;
  size_t row = (size_t)blockIdx.x * 4 + wave;   // over B*S*H
  int hh = (int)(row & 7);
  size_t idx = row * 64 + lane;
  float hv = ov[idx] * hsv[idx];
  float s = hv, s2 = hv * hv;
  #pragma unroll
  for (int mm = 32; mm > 0; mm >>= 1) { s += __shfl_xor(s, mm, 64); s2 += __shfl_xor(s2, mm, 64); }
  float mu  = s * (1.f / 64.f);
  float var = s2 * (1.f / 64.f) - mu * mu;
  float r = rsqrtf(var + EPSq);
  float hn = (hv - mu) * r * mg[hh * 64 + lane] + mb[hh * 64 + lane];
  float rv = rt[idx];
  float y = (hn + xs[idx]) * (rv / (1.f + expf(-rv)));
  bf16 h, l; split2(y, h, l);
  pdh[idx] = h; pdl[idx] = l;
}

extern "C" void kernel_launch(void* const* d_in, const int* in_sizes, int n_in,
                              void* d_out, int out_size, void* d_ws, size_t ws_size,
                              hipStream_t stream)
{
  const float* x      = (const float*)d_in[0];
  const float* ln_g   = (const float*)d_in[1];
  const float* ln_b   = (const float*)d_in[2];
  const float* mh_g   = (const float*)d_in[3];
  const float* mh_b   = (const float*)d_in[4];
  const float* W_up_l = (const float*)d_in[5];
  const float* b_up_l = (const float*)d_in[6];
  const float* W_up_r = (const float*)d_in[7];
  const float* b_up_r = (const float*)d_in[8];
  const float* W_down = (const float*)d_in[9];
  const float* b_down = (const float*)d_in[10];
  const float* conv_w = (const float*)d_in[11];
  const float* conv_b = (const float*)d_in[12];
  const float* W_skip = (const float*)d_in[13];
  const float* b_skip = (const float*)d_in[14];
  const float* W_i    = (const float*)d_in[15];
  const float* b_i    = (const float*)d_in[16];
  const float* W_f    = (const float*)d_in[17];
  const float* b_f    = (const float*)d_in[18];
  const float* W_o    = (const float*)d_in[19];
  const float* b_o    = (const float*)d_in[20];
  const float* W_q    = (const float*)d_in[21];
  const float* b_q    = (const float*)d_in[22];
  const float* W_k    = (const float*)d_in[23];
  const float* b_k    = (const float*)d_in[24];
  const float* W_v    = (const float*)d_in[25];
  const float* b_v    = (const float*)d_in[26];
  float* out = (float*)d_out;

  const size_t MB = 1u << 20;
  if (ws_size < 193 * MB) return;

  char* base = (char*)d_ws;
  bf16* whi = (bf16*)base;             // 0..16 MB
  bf16* wlo = (bf16*)(base + 16*MB);   // 16..32 MB
  bf16* xnh = (bf16*)(base + 32*MB);
  bf16* xnl = (bf16*)(base + 48*MB);
  bf16* xth = (bf16*)(base + 64*MB);
  bf16* xtl = (bf16*)(base + 96*MB);
  bf16* xch = (bf16*)(base + 128*MB);
  bf16* xcl = (bf16*)(base + 160*MB);
  // reuse of dead regions:
  float* vb  = (float*)(base + 32*MB); // xn region
  float* ob  = (float*)(base + 48*MB);
  float* xs  = (float*)(base + 64*MB); // xt region
  float* qb  = (float*)(base + 80*MB);
  float* kb  = (float*)(base + 96*MB);
  bf16*  pdh = (bf16*)(base + 112*MB);
  bf16*  pdl = (bf16*)(base + 120*MB);
  // chunkwise-recurrence buffers in dead xc region (after ifk):
  float* kvg    = (float*)(base + 128*MB);            // 16 MB
  float* boundC = (float*)(base + 144*MB);            // 16 MB
  float* bg     = (float*)(base + 160*MB);            // 256 KB
  float* ksumg  = (float*)(base + 160*MB + 256*1024); // 256 KB
  float* boundN = (float*)(base + 160*MB + 512*1024); // 256 KB
  float* FcMc   = (float*)(base + 160*MB + 768*1024); // 8 KB
  float* boundM = (float*)(base + 160*MB + 776*1024); // 4 KB
  float* ip  = (float*)(base + 192*MB);
  float* fpb = (float*)(base + 192*MB + 256*1024);
  float* rt  = out;                    // d_out scratch; down GEMM overwrites
  float* hsb = qb;                     // hs aliases qb (chunkC stages q first)

  const int Mrows = Bq * Sq;   // 8192
  const int BIG = 1 << 30;

  auto cvtw = [&](const float* s, size_t off, int n) {
    cvtw_kernel<<<dim3((n/4 + 255)/256), dim3(256), 0, stream>>>(s, whi + off, wlo + off, n/4);
  };
  cvtw(W_up_l, 0,           2048*1024);
  cvtw(W_up_r, 2048*1024,   512*1024);
  cvtw(W_v,    2621440,           512*2048);
  cvtw(W_o,    2621440 + 1048576, 512*2048);
  cvtw(W_skip, 4718592,             512*2048);
  cvtw(W_q,    4718592 + 1048576,   512*2048);
  cvtw(W_k,    4718592 + 2*1048576, 512*2048);
  cvtw(W_down, 7864320,   1024*512);

  ln_kernel<<<dim3(Mrows), dim3(256), 0, stream>>>(x, ln_g, ln_b, xnh, xnl);

  gemm_x3<<<dim3(20, 64), dim3(256), 0, stream>>>(
      xnh, xnl, whi, wlo, 1024, 2048, BIG, nullptr,
      b_up_l, nullptr, xth, xtl, 2048, 1.f, 0,
      b_up_r, rt, nullptr, nullptr, 512, 1.f, 0,
      nullptr, nullptr, nullptr, nullptr, 1, 1.f, 0);

  gemm_x3<<<dim3(8, 64), dim3(256), 0, stream>>>(
      xth, xtl, whi + 2621440, wlo + 2621440, 2048, 512, BIG, nullptr,
      b_v, vb, nullptr, nullptr, 512, 1.f, 0,
      b_o, ob, nullptr, nullptr, 512, 1.f, 1,
      nullptr, nullptr, nullptr, nullptr, 1, 1.f, 0);

  int convTotal = Mrows * Pq;
  conv_kernel<<<dim3(convTotal / 256), dim3(256), 0, stream>>>(
      xth, xtl, conv_w, conv_b, xch, xcl, convTotal);

  gemm_x3<<<dim3(12, 64), dim3(256), 0, stream>>>(
      xch, xcl, whi + 4718592, wlo + 4718592, 2048, 512, 1024, nullptr,
      b_skip, xs, nullptr, nullptr, 512, 1.f, 0,
      b_q, qb, nullptr, nullptr, 512, 1.f, 0,
      b_k, kb, nullptr, nullptr, 512, 0.125f, 0);

  ifk_kernel<<<dim3(Mrows), dim3(256), 0, stream>>>(
      xch, xcl, W_i, b_i, W_f, b_f, ip, fpb);
  // xc dead from here; chunk buffers live in its region

  chunkA_kernel<<<dim3(Bq * Hq * NCq), dim3(256), 0, stream>>>(
      kb, vb, ip, fpb, bg, FcMc, kvg, ksumg);
  chunkB_kernel<<<dim3(Bq * Hq), dim3(256), 0, stream>>>(
      kvg, ksumg, FcMc, boundC, boundN, boundM);
  chunkC_kernel<<<dim3(Bq * Hq * NCq), dim3(256), 0, stream>>>(
      qb, kb, vb, bg, boundC, boundN, boundM, hsb);

  epi_kernel<<<dim3(Mrows * Hq / 4), dim3(256), 0, stream>>>(
      hsb, ob, xs, rt, mh_g, mh_b, pdh, pdl);

  gemm_x3<<<dim3(8, 64), dim3(256), 0, stream>>>(
      pdh, pdl, whi + 7864320, wlo + 7864320, 512, BIG, BIG, x,
      b_down, out, nullptr, nullptr, 1024, 1.f, 0,
      nullptr, nullptr, nullptr, nullptr, 1, 1.f, 0,
      nullptr, nullptr, nullptr, nullptr, 1, 1.f, 0);
}

// Round 6
// 1042.942 us; speedup vs baseline: 3.5141x; 1.0069x over previous
//
#include <hip/hip_runtime.h>
#include <hip/hip_bf16.h>
#include <math.h>

#define Bq 8
#define Sq 1024
#define Dq 1024
#define Hq 8
#define HDq 64
#define HIDq 512
#define Pq 2048
#define EPSq 1e-6f
#define CAPq 15.0f
#define NCq 16    // chunks per sequence
#define CLq 64    // chunk length

typedef __attribute__((ext_vector_type(8))) short short8;
typedef __attribute__((ext_vector_type(4))) float f32x4v;
typedef __hip_bfloat16 bf16;

__device__ inline void split2(float v, bf16& h, bf16& l) {
  h = __float2bfloat16(v);
  l = __float2bfloat16(v - __bfloat162float(h));
}

// async 16B/lane HBM -> LDS DMA; LDS dest = wave-uniform base + lane*16
__device__ inline void async_ld16(const short* g, short* l) {
  __builtin_amdgcn_global_load_lds(
      (const __attribute__((address_space(1))) void*)g,
      (__attribute__((address_space(3))) void*)l,
      16, 0, 0);
}

// -------- fused weight split: all 8 weights -> packed hi/lo arenas ----------
// unit = 4 elements; segments packed contiguously so dst offset = unit*4.
__global__ __launch_bounds__(256) void cvtw_all(
    const float* __restrict__ s0, const float* __restrict__ s1,
    const float* __restrict__ s2, const float* __restrict__ s3,
    const float* __restrict__ s4, const float* __restrict__ s5,
    const float* __restrict__ s6, const float* __restrict__ s7,
    bf16* __restrict__ hi, bf16* __restrict__ lo)
{
  int u = blockIdx.x * 256 + threadIdx.x;   // 0 .. 2097151
  const float* src; int segBase;
  if      (u <  524288) { src = s0; segBase = 0;       }
  else if (u <  655360) { src = s1; segBase = 524288;  }
  else if (u <  917504) { src = s2; segBase = 655360;  }
  else if (u < 1179648) { src = s3; segBase = 917504;  }
  else if (u < 1441792) { src = s4; segBase = 1179648; }
  else if (u < 1703936) { src = s5; segBase = 1441792; }
  else if (u < 1966080) { src = s6; segBase = 1703936; }
  else                  { src = s7; segBase = 1966080; }
  float4 v = ((const float4*)src)[u - segBase];
  size_t o = (size_t)u * 4;
  bf16 h, l;
  split2(v.x, h, l); hi[o+0] = h; lo[o+0] = l;
  split2(v.y, h, l); hi[o+1] = h; lo[o+1] = l;
  split2(v.z, h, l); hi[o+2] = h; lo[o+2] = l;
  split2(v.w, h, l); hi[o+3] = h; lo[o+3] = l;
}

// ---------------- LayerNorm over D=1024 -> hi/lo bf16 out ----------------
__global__ __launch_bounds__(256) void ln_kernel(const float* __restrict__ x,
    const float* __restrict__ g, const float* __restrict__ b,
    bf16* __restrict__ yh, bf16* __restrict__ yl)
{
  int row = blockIdx.x;
  int tid = threadIdx.x;
  const float* xr = x + (size_t)row * Dq;
  float v[4]; float s = 0.f, s2 = 0.f;
  #pragma unroll
  for (int i = 0; i < 4; i++) { v[i] = xr[tid + 256*i]; s += v[i]; s2 += v[i]*v[i]; }
  #pragma unroll
  for (int mm = 32; mm > 0; mm >>= 1) { s += __shfl_xor(s, mm, 64); s2 += __shfl_xor(s2, mm, 64); }
  __shared__ float rs[4], rs2[4];
  int lane = tid & 63, wave = tid >> 6;
  if (lane == 0) { rs[wave] = s; rs2[wave] = s2; }
  __syncthreads();
  s  = rs[0] + rs[1] + rs[2] + rs[3];
  s2 = rs2[0] + rs2[1] + rs2[2] + rs2[3];
  float mu  = s * (1.f / Dq);
  float var = s2 * (1.f / Dq) - mu * mu;
  float r = rsqrtf(var + EPSq);
  #pragma unroll
  for (int i = 0; i < 4; i++) {
    int c = tid + 256*i;
    float y = (v[i] - mu) * r * g[c] + b[c];
    bf16 h, l; split2(y, h, l);
    yh[(size_t)row * Dq + c] = h;
    yl[(size_t)row * Dq + c] = l;
  }
}

// ------------- bf16x3 MFMA GEMM, 128x128 tile, BK=32, 256 thr --------------
// Staging via global_load_lds (16B/lane DMA, m97-style): each wave stages
// 2 segments of 16 rows per buffer per K-iter; no VGPR round-trip.
__global__ __launch_bounds__(256) void gemm_x3(
    const bf16* __restrict__ Ahi, const bf16* __restrict__ Alo,
    const bf16* __restrict__ Whi, const bf16* __restrict__ Wlo,
    int Kd, int start1, int start2, const float* __restrict__ resid,
    const float* bias0, float* f0, bf16* h0, bf16* l0, int w0, float sc0, int a0,
    const float* bias1, float* f1, bf16* h1, bf16* l1, int w1, float sc1, int a1,
    const float* bias2, float* f2, bf16* h2, bf16* l2, int w2, float sc2, int a2)
{
  __shared__ short Ah[128 * 32];
  __shared__ short Al[128 * 32];
  __shared__ short Bh[128 * 32];
  __shared__ short Bl[128 * 32];
  int tid = threadIdx.x;
  int lane = tid & 63, wave = tid >> 6;
  int wr = wave >> 1, wc = wave & 1;            // wave tile 64x64
  int rowBase = blockIdx.y * 128;
  int colBase = blockIdx.x * 128;

  // DMA staging geometry: seg = 16 rows = 1024 B; this wave stages segs
  // {2*wave, 2*wave+1} of each buffer. Per-lane global offset within a seg:
  int seg0 = wave * 2, seg1 = wave * 2 + 1;
  int sr0 = seg0 * 16 + (lane >> 2);
  int sr1 = seg1 * 16 + (lane >> 2);
  int sc  = (lane & 3) * 8;

  const short* Ahg = (const short*)Ahi + (size_t)rowBase * Kd;
  const short* Alg = (const short*)Alo + (size_t)rowBase * Kd;
  const short* Bhg = (const short*)Whi + (size_t)colBase * Kd;
  const short* Blg = (const short*)Wlo + (size_t)colBase * Kd;

  size_t g0 = (size_t)sr0 * Kd + sc;
  size_t g1 = (size_t)sr1 * Kd + sc;
  short* lA0 = &Ah[seg0 * 512]; short* lA1 = &Ah[seg1 * 512];
  short* lB0 = &Al[seg0 * 512]; short* lB1 = &Al[seg1 * 512];
  short* lC0 = &Bh[seg0 * 512]; short* lC1 = &Bh[seg1 * 512];
  short* lD0 = &Bl[seg0 * 512]; short* lD1 = &Bl[seg1 * 512];

  f32x4v acc[4][4];
  #pragma unroll
  for (int i = 0; i < 4; i++)
    #pragma unroll
    for (int j = 0; j < 4; j++) acc[i][j] = (f32x4v){0.f, 0.f, 0.f, 0.f};

  int fk = (lane >> 4) * 8;
  int fr = lane & 15;

  for (int k0 = 0; k0 < Kd; k0 += 32) {
    __syncthreads();                       // prior iter's LDS reads complete
    async_ld16(Ahg + g0 + k0, lA0);
    async_ld16(Ahg + g1 + k0, lA1);
    async_ld16(Alg + g0 + k0, lB0);
    async_ld16(Alg + g1 + k0, lB1);
    async_ld16(Bhg + g0 + k0, lC0);
    async_ld16(Bhg + g1 + k0, lC1);
    async_ld16(Blg + g0 + k0, lD0);
    async_ld16(Blg + g1 + k0, lD1);
    __syncthreads();                       // vmcnt(0) drain + barrier
    short8 afh[4], afl[4], bfh[4], bfl[4];
    #pragma unroll
    for (int mi = 0; mi < 4; mi++) {
      afh[mi] = *(const short8*)&Ah[(wr * 64 + mi * 16 + fr) * 32 + fk];
      afl[mi] = *(const short8*)&Al[(wr * 64 + mi * 16 + fr) * 32 + fk];
    }
    #pragma unroll
    for (int ni = 0; ni < 4; ni++) {
      bfh[ni] = *(const short8*)&Bh[(wc * 64 + ni * 16 + fr) * 32 + fk];
      bfl[ni] = *(const short8*)&Bl[(wc * 64 + ni * 16 + fr) * 32 + fk];
    }
    #pragma unroll
    for (int mi = 0; mi < 4; mi++)
      #pragma unroll
      for (int ni = 0; ni < 4; ni++)
        acc[mi][ni] = __builtin_amdgcn_mfma_f32_16x16x32_bf16(afh[mi], bfh[ni], acc[mi][ni], 0, 0, 0);
    #pragma unroll
    for (int mi = 0; mi < 4; mi++)
      #pragma unroll
      for (int ni = 0; ni < 4; ni++)
        acc[mi][ni] = __builtin_amdgcn_mfma_f32_16x16x32_bf16(afh[mi], bfl[ni], acc[mi][ni], 0, 0, 0);
    #pragma unroll
    for (int mi = 0; mi < 4; mi++)
      #pragma unroll
      for (int ni = 0; ni < 4; ni++)
        acc[mi][ni] = __builtin_amdgcn_mfma_f32_16x16x32_bf16(afl[mi], bfh[ni], acc[mi][ni], 0, 0, 0);
  }

  const float* bias; float* fOut; bf16* hOut; bf16* lOut; int segStart, segW; float sscale; int sact;
  if (colBase >= start2)      { bias=bias2; fOut=f2; hOut=h2; lOut=l2; segStart=start2; segW=w2; sscale=sc2; sact=a2; }
  else if (colBase >= start1) { bias=bias1; fOut=f1; hOut=h1; lOut=l1; segStart=start1; segW=w1; sscale=sc1; sact=a1; }
  else                        { bias=bias0; fOut=f0; hOut=h0; lOut=l0; segStart=0;      segW=w0; sscale=sc0; sact=a0; }

  int cr = (lane >> 4) * 4;
  int cc = lane & 15;
  #pragma unroll
  for (int mi = 0; mi < 4; mi++) {
    #pragma unroll
    for (int ni = 0; ni < 4; ni++) {
      int col  = colBase + wc * 64 + ni * 16 + cc;
      int colL = col - segStart;
      float bv = bias[colL];
      #pragma unroll
      for (int j = 0; j < 4; j++) {
        int row = rowBase + wr * 64 + mi * 16 + cr + j;
        float val = (acc[mi][ni][j] + bv) * sscale;
        if (sact) val = 1.f / (1.f + expf(-val));
        if (resid && segStart == 0) val += resid[(size_t)row * segW + colL];
        size_t oidx = (size_t)row * segW + colL;
        if (fOut) fOut[oidx] = val;
        if (hOut) {
          bf16 h, l; split2(val, h, l);
          hOut[oidx] = h; lOut[oidx] = l;
        }
      }
    }
  }
}

// ---------------- causal conv over FEATURE axis (K=4) + SiLU ----------------
__global__ __launch_bounds__(256) void conv_kernel(const bf16* __restrict__ xth,
    const bf16* __restrict__ xtl, const float* __restrict__ cw,
    const float* __restrict__ cb, bf16* __restrict__ xch, bf16* __restrict__ xcl,
    int total)
{
  int idx = blockIdx.x * 256 + threadIdx.x;
  if (idx >= total) return;
  int p = idx & (Pq - 1);
  #define XT(i) (__bfloat162float(xth[i]) + __bfloat162float(xtl[i]))
  float acc = cb[0] + cw[3] * XT(idx);
  if (p >= 1) acc += cw[2] * XT(idx - 1);
  if (p >= 2) acc += cw[1] * XT(idx - 2);
  if (p >= 3) acc += cw[0] * XT(idx - 3);
  #undef XT
  float y = acc / (1.f + expf(-acc));   // silu
  bf16 h, l; split2(y, h, l);
  xch[idx] = h; xcl[idx] = l;
}

// ---------------- skinny i/f gate GEMM (N=8 each) + softcap ----------------
__global__ __launch_bounds__(256) void ifk_kernel(const bf16* __restrict__ xch,
    const bf16* __restrict__ xcl,
    const float* __restrict__ Wi, const float* __restrict__ bi,
    const float* __restrict__ Wf, const float* __restrict__ bf_,
    float* __restrict__ ip, float* __restrict__ fp)
{
  int row = blockIdx.x;              // b*S + t
  int lane = threadIdx.x & 63, wave = threadIdx.x >> 6;
  size_t rb = (size_t)row * Pq;
  for (int oi = wave; oi < 16; oi += 4) {
    int hh = oi & 7;
    const float* Wrow = (oi < 8) ? (Wi + (size_t)hh * Pq) : (Wf + (size_t)hh * Pq);
    float s = 0.f;
    for (int j = lane; j < Pq; j += 64)
      s += (__bfloat162float(xch[rb + j]) + __bfloat162float(xcl[rb + j])) * Wrow[j];
    #pragma unroll
    for (int mm = 32; mm > 0; mm >>= 1) s += __shfl_xor(s, mm, 64);
    if (lane == 0) {
      float val = s + ((oi < 8) ? bi[hh] : bf_[hh]);
      val = CAPq * tanhf(val / CAPq);
      if (oi < 8) ip[(size_t)row * Hq + hh] = val;
      else        fp[(size_t)row * Hq + hh] = val;
    }
  }
}

// ===== chunkwise-parallel mLSTM recurrence =====
// b_s = i_s - cumF_s (chunk-local); Mrun_t = max(m_in, cummax_{s<=t} b_s);
// intra weight exp(b_s - Mrun_t); carry-in weight exp(m_in - Mrun_t).

// --- A: per-chunk scans + KV summary (grid: B*H*NC) ---
__global__ __launch_bounds__(256) void chunkA_kernel(const float* __restrict__ k,
    const float* __restrict__ v, const float* __restrict__ ip,
    const float* __restrict__ fp, float* __restrict__ bg,
    float* __restrict__ FcMc, float* __restrict__ kvg, float* __restrict__ ksumg)
{
  int blk = blockIdx.x;   // bh*NC + c
  int bh = blk >> 4, c = blk & 15;
  int b = bh >> 3, hh = bh & 7;
  int tid = threadIdx.x, lane = tid & 63, wave = tid >> 6;

  __shared__ float sK[64][64], sV[64][64], sW[64];

  size_t base = (size_t)b * Sq * 512 + (size_t)hh * 64 + (size_t)c * CLq * 512;
  #pragma unroll 4
  for (int i = 0; i < 16; i++) {
    int t = wave * 16 + i;
    sK[t][lane] = k[base + (size_t)t * 512 + lane];
    sV[t][lane] = v[base + (size_t)t * 512 + lane];
  }
  if (tid < 64) {
    size_t ifb = ((size_t)b * Sq + c * CLq + tid) * Hq + hh;
    float fv = fp[ifb], iv = ip[ifb];
    float cf = fv;                       // inclusive sum scan of f
    #pragma unroll
    for (int off = 1; off < 64; off <<= 1) {
      float t2 = __shfl_up(cf, off, 64);
      if (lane >= off) cf += t2;
    }
    float bs = iv - cf;
    float mx = bs;                       // inclusive max scan
    #pragma unroll
    for (int off = 1; off < 64; off <<= 1) {
      float t2 = __shfl_up(mx, off, 64);
      if (lane >= off) mx = fmaxf(mx, t2);
    }
    float Mc = __shfl(mx, 63, 64);
    bg[(size_t)blk * 64 + tid] = bs;
    sW[tid] = expf(bs - Mc);
    if (tid == 63) { FcMc[blk*2] = cf; FcMc[blk*2+1] = Mc; }
  }
  __syncthreads();
  // kv[d][e] = sum_s w_s * v_s[d] * k_s[e];  d=lane, e=wave*16+j
  float acc[16];
  #pragma unroll
  for (int j = 0; j < 16; j++) acc[j] = 0.f;
  for (int s = 0; s < 64; s++) {
    float wv = sW[s] * sV[s][lane];
    #pragma unroll
    for (int j = 0; j < 16; j++) acc[j] += wv * sK[s][wave*16+j];
  }
  float* kvp = kvg + (size_t)blk * 4096 + lane * 64 + wave * 16;
  #pragma unroll
  for (int j = 0; j < 16; j++) kvp[j] = acc[j];
  if (tid < 64) {
    float a = 0.f;
    for (int s = 0; s < 64; s++) a += sW[s] * sK[s][tid];
    ksumg[(size_t)blk * 64 + tid] = a;
  }
}

// --- B: boundary-state propagation, 16 sequential chunk steps (grid: B*H) ---
__global__ __launch_bounds__(256) void chunkB_kernel(const float* __restrict__ kvg,
    const float* __restrict__ ksumg, const float* __restrict__ FcMc,
    float* __restrict__ boundC, float* __restrict__ boundN, float* __restrict__ boundM)
{
  int bh = blockIdx.x;
  int tid = threadIdx.x, lane = tid & 63, wave = tid >> 6;
  float C[16];
  #pragma unroll
  for (int j = 0; j < 16; j++) C[j] = 0.f;
  float ne = 1.0f, m = 0.f;              // n0 = ones, m0 = 0
  for (int c = 0; c < NCq; c++) {
    size_t blk = (size_t)bh * NCq + c;
    float* bC = boundC + blk * 4096 + lane * 64 + wave * 16;
    #pragma unroll
    for (int j = 0; j < 16; j++) bC[j] = C[j];
    if (wave == 0) boundN[blk * 64 + lane] = ne;
    if (tid == 0)  boundM[blk] = m;
    float Fc = FcMc[blk * 2], Mc = FcMc[blk * 2 + 1];
    float mm = fmaxf(m, Mc);
    float a1 = expf(m - mm), a2 = expf(Mc - mm);
    const float* kv = kvg + blk * 4096 + lane * 64 + wave * 16;
    #pragma unroll
    for (int j = 0; j < 16; j++) C[j] = a1 * C[j] + a2 * kv[j];
    ne = a1 * ne + a2 * ksumg[blk * 64 + lane];
    m = Fc + mm;
  }
}

// --- C: intra-chunk parallel attention (grid: B*H*NC). q/hs may ALIAS. ---
__global__ __launch_bounds__(256) void chunkC_kernel(const float* q,
    const float* __restrict__ k, const float* __restrict__ v,
    const float* __restrict__ bg, const float* __restrict__ boundC,
    const float* __restrict__ boundN, const float* __restrict__ boundM,
    float* hs)
{
  int blk = blockIdx.x;   // bh*NC + c
  int bh = blk >> 4, c = blk & 15;
  int b = bh >> 3, hh = bh & 7;
  int tid = threadIdx.x, lane = tid & 63, wave = tid >> 6;

  __shared__ float sQ[64][65], sKV[64][65], sS[64][65];
  __shared__ float sB[64], sMr[64], sNin[64];

  size_t base = (size_t)b * Sq * 512 + (size_t)hh * 64 + (size_t)c * CLq * 512;
  #pragma unroll 4
  for (int i = 0; i < 16; i++) {
    int t = wave * 16 + i;
    sQ[t][lane]  = q[base + (size_t)t * 512 + lane];
    sKV[t][lane] = k[base + (size_t)t * 512 + lane];
  }
  float m_in = boundM[blk];
  if (tid < 64) {
    float bs = bg[(size_t)blk * 64 + tid];
    float mx = bs;
    #pragma unroll
    for (int off = 1; off < 64; off <<= 1) {
      float t2 = __shfl_up(mx, off, 64);
      if (lane >= off) mx = fmaxf(mx, t2);
    }
    sB[tid]   = bs;
    sMr[tid]  = fmaxf(m_in, mx);
    sNin[tid] = boundN[(size_t)blk * 64 + tid];
  }
  __syncthreads();

  // S: thread (t=lane, s in wave*16..+16): raw dot then apply weight
  {
    int t = lane;
    float acc[16];
    #pragma unroll
    for (int j = 0; j < 16; j++) acc[j] = 0.f;
    for (int d = 0; d < 64; d++) {
      float qv = sQ[t][d];
      #pragma unroll
      for (int j = 0; j < 16; j++) acc[j] += qv * sKV[wave*16+j][d];
    }
    float Mr = sMr[t];
    #pragma unroll
    for (int j = 0; j < 16; j++) {
      int s = wave * 16 + j;
      float w = (s <= t) ? expf(sB[s] - Mr) : 0.f;
      sS[t][s] = w * acc[j];
    }
  }
  __syncthreads();
  #pragma unroll 4
  for (int i = 0; i < 16; i++) {       // restage v over k
    int t = wave * 16 + i;
    sKV[t][lane] = v[base + (size_t)t * 512 + lane];
  }
  __syncthreads();

  // output: thread (t=lane, d in wave*16..+16)
  {
    int t = lane;
    float Mr = sMr[t];
    float bfac = expf(m_in - Mr);
    float den = 0.f;
    for (int d = 0; d < 64; d++) den += sNin[d] * sQ[t][d];
    den *= bfac;
    float num[16];
    #pragma unroll
    for (int j = 0; j < 16; j++) num[j] = 0.f;
    const float* Crow = boundC + (size_t)blk * 4096;
    for (int e = 0; e < 64; e++) {
      float qv = sQ[t][e];
      #pragma unroll
      for (int j = 0; j < 16; j++)
        num[j] += Crow[(size_t)(wave*16+j) * 64 + e] * qv;
    }
    #pragma unroll
    for (int j = 0; j < 16; j++) num[j] *= bfac;
    for (int s = 0; s < 64; s++) {
      float ws = sS[t][s];
      den += ws;
      #pragma unroll
      for (int j = 0; j < 16; j++) num[j] += ws * sKV[s][wave*16+j];
    }
    den = fmaxf(den, 1.0f);
    float o[16];
    #pragma unroll
    for (int j = 0; j < 16; j++) o[j] = num[j] / den;
    float* hp = hs + base + (size_t)t * 512 + wave * 16;
    #pragma unroll
    for (int j4 = 0; j4 < 4; j4++)
      ((float4*)hp)[j4] = ((float4*)o)[j4];
  }
}

// ------ epilogue: h=o*hs; per-head LN; (hn+skip)*silu(r) -> hi/lo bf16 ------
__global__ __launch_bounds__(256) void epi_kernel(const float* __restrict__ hsv,
    const float* __restrict__ ov, const float* __restrict__ xs,
    const float* __restrict__ rt, const float* __restrict__ mg,
    const float* __restrict__ mb, bf16* __restrict__ pdh, bf16* __restrict__ pdl)
{
  int tid = threadIdx.x;
  int lane = tid & 63, wave = tid >> 6;
  size_t row = (size_t)blockIdx.x * 4 + wave;   // over B*S*H
  int hh = (int)(row & 7);
  size_t idx = row * 64 + lane;
  float hv = ov[idx] * hsv[idx];
  float s = hv, s2 = hv * hv;
  #pragma unroll
  for (int mm = 32; mm > 0; mm >>= 1) { s += __shfl_xor(s, mm, 64); s2 += __shfl_xor(s2, mm, 64); }
  float mu  = s * (1.f / 64.f);
  float var = s2 * (1.f / 64.f) - mu * mu;
  float r = rsqrtf(var + EPSq);
  float hn = (hv - mu) * r * mg[hh * 64 + lane] + mb[hh * 64 + lane];
  float rv = rt[idx];
  float y = (hn + xs[idx]) * (rv / (1.f + expf(-rv)));
  bf16 h, l; split2(y, h, l);
  pdh[idx] = h; pdl[idx] = l;
}

extern "C" void kernel_launch(void* const* d_in, const int* in_sizes, int n_in,
                              void* d_out, int out_size, void* d_ws, size_t ws_size,
                              hipStream_t stream)
{
  const float* x      = (const float*)d_in[0];
  const float* ln_g   = (const float*)d_in[1];
  const float* ln_b   = (const float*)d_in[2];
  const float* mh_g   = (const float*)d_in[3];
  const float* mh_b   = (const float*)d_in[4];
  const float* W_up_l = (const float*)d_in[5];
  const float* b_up_l = (const float*)d_in[6];
  const float* W_up_r = (const float*)d_in[7];
  const float* b_up_r = (const float*)d_in[8];
  const float* W_down = (const float*)d_in[9];
  const float* b_down = (const float*)d_in[10];
  const float* conv_w = (const float*)d_in[11];
  const float* conv_b = (const float*)d_in[12];
  const float* W_skip = (const float*)d_in[13];
  const float* b_skip = (const float*)d_in[14];
  const float* W_i    = (const float*)d_in[15];
  const float* b_i    = (const float*)d_in[16];
  const float* W_f    = (const float*)d_in[17];
  const float* b_f    = (const float*)d_in[18];
  const float* W_o    = (const float*)d_in[19];
  const float* b_o    = (const float*)d_in[20];
  const float* W_q    = (const float*)d_in[21];
  const float* b_q    = (const float*)d_in[22];
  const float* W_k    = (const float*)d_in[23];
  const float* b_k    = (const float*)d_in[24];
  const float* W_v    = (const float*)d_in[25];
  const float* b_v    = (const float*)d_in[26];
  float* out = (float*)d_out;

  const size_t MB = 1u << 20;
  if (ws_size < 193 * MB) return;

  char* base = (char*)d_ws;
  bf16* whi = (bf16*)base;             // 0..16 MB
  bf16* wlo = (bf16*)(base + 16*MB);   // 16..32 MB
  bf16* xnh = (bf16*)(base + 32*MB);
  bf16* xnl = (bf16*)(base + 48*MB);
  bf16* xth = (bf16*)(base + 64*MB);
  bf16* xtl = (bf16*)(base + 96*MB);
  bf16* xch = (bf16*)(base + 128*MB);
  bf16* xcl = (bf16*)(base + 160*MB);
  // reuse of dead regions:
  float* vb  = (float*)(base + 32*MB); // xn region
  float* ob  = (float*)(base + 48*MB);
  float* xs  = (float*)(base + 64*MB); // xt region
  float* qb  = (float*)(base + 80*MB);
  float* kb  = (float*)(base + 96*MB);
  bf16*  pdh = (bf16*)(base + 112*MB);
  bf16*  pdl = (bf16*)(base + 120*MB);
  // chunkwise-recurrence buffers in dead xc region (after ifk):
  float* kvg    = (float*)(base + 128*MB);            // 16 MB
  float* boundC = (float*)(base + 144*MB);            // 16 MB
  float* bg     = (float*)(base + 160*MB);            // 256 KB
  float* ksumg  = (float*)(base + 160*MB + 256*1024); // 256 KB
  float* boundN = (float*)(base + 160*MB + 512*1024); // 256 KB
  float* FcMc   = (float*)(base + 160*MB + 768*1024); // 8 KB
  float* boundM = (float*)(base + 160*MB + 776*1024); // 4 KB
  float* ip  = (float*)(base + 192*MB);
  float* fpb = (float*)(base + 192*MB + 256*1024);
  float* rt  = out;                    // d_out scratch; down GEMM overwrites
  float* hsb = qb;                     // hs aliases qb (chunkC stages q first)

  const int Mrows = Bq * Sq;   // 8192
  const int BIG = 1 << 30;

  // single fused weight-split launch (segments packed in arena order)
  cvtw_all<<<dim3(8192), dim3(256), 0, stream>>>(
      W_up_l, W_up_r, W_v, W_o, W_skip, W_q, W_k, W_down, whi, wlo);

  ln_kernel<<<dim3(Mrows), dim3(256), 0, stream>>>(x, ln_g, ln_b, xnh, xnl);

  gemm_x3<<<dim3(20, 64), dim3(256), 0, stream>>>(
      xnh, xnl, whi, wlo, 1024, 2048, BIG, nullptr,
      b_up_l, nullptr, xth, xtl, 2048, 1.f, 0,
      b_up_r, rt, nullptr, nullptr, 512, 1.f, 0,
      nullptr, nullptr, nullptr, nullptr, 1, 1.f, 0);

  gemm_x3<<<dim3(8, 64), dim3(256), 0, stream>>>(
      xth, xtl, whi + 2621440, wlo + 2621440, 2048, 512, BIG, nullptr,
      b_v, vb, nullptr, nullptr, 512, 1.f, 0,
      b_o, ob, nullptr, nullptr, 512, 1.f, 1,
      nullptr, nullptr, nullptr, nullptr, 1, 1.f, 0);

  int convTotal = Mrows * Pq;
  conv_kernel<<<dim3(convTotal / 256), dim3(256), 0, stream>>>(
      xth, xtl, conv_w, conv_b, xch, xcl, convTotal);

  gemm_x3<<<dim3(12, 64), dim3(256), 0, stream>>>(
      xch, xcl, whi + 4718592, wlo + 4718592, 2048, 512, 1024, nullptr,
      b_skip, xs, nullptr, nullptr, 512, 1.f, 0,
      b_q, qb, nullptr, nullptr, 512, 1.f, 0,
      b_k, kb, nullptr, nullptr, 512, 0.125f, 0);

  ifk_kernel<<<dim3(Mrows), dim3(256), 0, stream>>>(
      xch, xcl, W_i, b_i, W_f, b_f, ip, fpb);
  // xc dead from here; chunk buffers live in its region

  chunkA_kernel<<<dim3(Bq * Hq * NCq), dim3(256), 0, stream>>>(
      kb, vb, ip, fpb, bg, FcMc, kvg, ksumg);
  chunkB_kernel<<<dim3(Bq * Hq), dim3(256), 0, stream>>>(
      kvg, ksumg, FcMc, boundC, boundN, boundM);
  chunkC_kernel<<<dim3(Bq * Hq * NCq), dim3(256), 0, stream>>>(
      qb, kb, vb, bg, boundC, boundN, boundM, hsb);

  epi_kernel<<<dim3(Mrows * Hq / 4), dim3(256), 0, stream>>>(
      hsb, ob, xs, rt, mh_g, mh_b, pdh, pdl);

  gemm_x3<<<dim3(8, 64), dim3(256), 0, stream>>>(
      pdh, pdl, whi + 7864320, wlo + 7864320, 512, BIG, BIG, x,
      b_down, out, nullptr, nullptr, 1024, 1.f, 0,
      nullptr, nullptr, nullptr, nullptr, 1, 1.f, 0,
      nullptr, nullptr, nullptr, nullptr, 1, 1.f, 0);
}

// Round 7
// 1040.328 us; speedup vs baseline: 3.5230x; 1.0025x over previous
//
#include <hip/hip_runtime.h>
#include <hip/hip_bf16.h>
#include <math.h>

#define Bq 8
#define Sq 1024
#define Dq 1024
#define Hq 8
#define HDq 64
#define HIDq 512
#define Pq 2048
#define EPSq 1e-6f
#define CAPq 15.0f
#define NCq 16    // chunks per sequence
#define CLq 64    // chunk length
#define LDST 40   // LDS row stride in shorts (80 B = 20 banks: conflict-free, 16B-aligned)

typedef __attribute__((ext_vector_type(8))) short short8;
typedef __attribute__((ext_vector_type(4))) float f32x4v;
typedef __hip_bfloat16 bf16;

__device__ inline void split2(float v, bf16& h, bf16& l) {
  h = __float2bfloat16(v);
  l = __float2bfloat16(v - __bfloat162float(h));
}

// -------- fused weight split: all 8 weights -> packed hi/lo arenas ----------
__global__ __launch_bounds__(256) void cvtw_all(
    const float* __restrict__ s0, const float* __restrict__ s1,
    const float* __restrict__ s2, const float* __restrict__ s3,
    const float* __restrict__ s4, const float* __restrict__ s5,
    const float* __restrict__ s6, const float* __restrict__ s7,
    bf16* __restrict__ hi, bf16* __restrict__ lo)
{
  int u = blockIdx.x * 256 + threadIdx.x;   // 0 .. 2097151
  const float* src; int segBase;
  if      (u <  524288) { src = s0; segBase = 0;       }
  else if (u <  655360) { src = s1; segBase = 524288;  }
  else if (u <  917504) { src = s2; segBase = 655360;  }
  else if (u < 1179648) { src = s3; segBase = 917504;  }
  else if (u < 1441792) { src = s4; segBase = 1179648; }
  else if (u < 1703936) { src = s5; segBase = 1441792; }
  else if (u < 1966080) { src = s6; segBase = 1703936; }
  else                  { src = s7; segBase = 1966080; }
  float4 v = ((const float4*)src)[u - segBase];
  size_t o = (size_t)u * 4;
  bf16 h, l;
  split2(v.x, h, l); hi[o+0] = h; lo[o+0] = l;
  split2(v.y, h, l); hi[o+1] = h; lo[o+1] = l;
  split2(v.z, h, l); hi[o+2] = h; lo[o+2] = l;
  split2(v.w, h, l); hi[o+3] = h; lo[o+3] = l;
}

// ---------------- LayerNorm over D=1024 -> hi/lo bf16 out ----------------
__global__ __launch_bounds__(256) void ln_kernel(const float* __restrict__ x,
    const float* __restrict__ g, const float* __restrict__ b,
    bf16* __restrict__ yh, bf16* __restrict__ yl)
{
  int row = blockIdx.x;
  int tid = threadIdx.x;
  const float* xr = x + (size_t)row * Dq;
  float v[4]; float s = 0.f, s2 = 0.f;
  #pragma unroll
  for (int i = 0; i < 4; i++) { v[i] = xr[tid + 256*i]; s += v[i]; s2 += v[i]*v[i]; }
  #pragma unroll
  for (int mm = 32; mm > 0; mm >>= 1) { s += __shfl_xor(s, mm, 64); s2 += __shfl_xor(s2, mm, 64); }
  __shared__ float rs[4], rs2[4];
  int lane = tid & 63, wave = tid >> 6;
  if (lane == 0) { rs[wave] = s; rs2[wave] = s2; }
  __syncthreads();
  s  = rs[0] + rs[1] + rs[2] + rs[3];
  s2 = rs2[0] + rs2[1] + rs2[2] + rs2[3];
  float mu  = s * (1.f / Dq);
  float var = s2 * (1.f / Dq) - mu * mu;
  float r = rsqrtf(var + EPSq);
  #pragma unroll
  for (int i = 0; i < 4; i++) {
    int c = tid + 256*i;
    float y = (v[i] - mu) * r * g[c] + b[c];
    bf16 h, l; split2(y, h, l);
    yh[(size_t)row * Dq + c] = h;
    yl[(size_t)row * Dq + c] = l;
  }
}

// ------------- bf16x3 MFMA GEMM, 128x128 tile, BK=32, 256 thr --------------
// LDS rows padded to LDST=40 shorts (80 B = 20 banks): quarter-wave b128
// reads hit each bank exactly 2x (free); staging writes uniform 8/bank.
__global__ __launch_bounds__(256) void gemm_x3(
    const bf16* __restrict__ Ahi, const bf16* __restrict__ Alo,
    const bf16* __restrict__ Whi, const bf16* __restrict__ Wlo,
    int Kd, int start1, int start2, const float* __restrict__ resid,
    const float* bias0, float* f0, bf16* h0, bf16* l0, int w0, float sc0, int a0,
    const float* bias1, float* f1, bf16* h1, bf16* l1, int w1, float sc1, int a1,
    const float* bias2, float* f2, bf16* h2, bf16* l2, int w2, float sc2, int a2)
{
  __shared__ short Ah[128 * LDST];
  __shared__ short Al[128 * LDST];
  __shared__ short Bh[128 * LDST];
  __shared__ short Bl[128 * LDST];
  int tid = threadIdx.x;
  int lane = tid & 63, wave = tid >> 6;
  int wr = wave >> 1, wc = wave & 1;            // wave tile 64x64
  int rowBase = blockIdx.y * 128;
  int colBase = blockIdx.x * 128;

  int sk  = (tid & 3) * 8;
  int sr0 = tid >> 2;          // 0..63
  int sr1 = 64 + sr0;

  const short* Ahg = (const short*)Ahi + (size_t)rowBase * Kd;
  const short* Alg = (const short*)Alo + (size_t)rowBase * Kd;
  const short* Bhg = (const short*)Whi + (size_t)colBase * Kd;
  const short* Blg = (const short*)Wlo + (size_t)colBase * Kd;

  f32x4v acc[4][4];
  #pragma unroll
  for (int i = 0; i < 4; i++)
    #pragma unroll
    for (int j = 0; j < 4; j++) acc[i][j] = (f32x4v){0.f, 0.f, 0.f, 0.f};

  int fk = (lane >> 4) * 8;
  int fr = lane & 15;

  for (int k0 = 0; k0 < Kd; k0 += 32) {
    short8 ah0 = *(const short8*)(Ahg + (size_t)sr0 * Kd + k0 + sk);
    short8 ah1 = *(const short8*)(Ahg + (size_t)sr1 * Kd + k0 + sk);
    short8 al0 = *(const short8*)(Alg + (size_t)sr0 * Kd + k0 + sk);
    short8 al1 = *(const short8*)(Alg + (size_t)sr1 * Kd + k0 + sk);
    short8 bh0 = *(const short8*)(Bhg + (size_t)sr0 * Kd + k0 + sk);
    short8 bh1 = *(const short8*)(Bhg + (size_t)sr1 * Kd + k0 + sk);
    short8 bl0 = *(const short8*)(Blg + (size_t)sr0 * Kd + k0 + sk);
    short8 bl1 = *(const short8*)(Blg + (size_t)sr1 * Kd + k0 + sk);
    __syncthreads();   // prior iteration's LDS reads done
    *(short8*)&Ah[sr0 * LDST + sk] = ah0;
    *(short8*)&Ah[sr1 * LDST + sk] = ah1;
    *(short8*)&Al[sr0 * LDST + sk] = al0;
    *(short8*)&Al[sr1 * LDST + sk] = al1;
    *(short8*)&Bh[sr0 * LDST + sk] = bh0;
    *(short8*)&Bh[sr1 * LDST + sk] = bh1;
    *(short8*)&Bl[sr0 * LDST + sk] = bl0;
    *(short8*)&Bl[sr1 * LDST + sk] = bl1;
    __syncthreads();
    short8 afh[4], afl[4], bfh[4], bfl[4];
    #pragma unroll
    for (int mi = 0; mi < 4; mi++) {
      afh[mi] = *(const short8*)&Ah[(wr * 64 + mi * 16 + fr) * LDST + fk];
      afl[mi] = *(const short8*)&Al[(wr * 64 + mi * 16 + fr) * LDST + fk];
    }
    #pragma unroll
    for (int ni = 0; ni < 4; ni++) {
      bfh[ni] = *(const short8*)&Bh[(wc * 64 + ni * 16 + fr) * LDST + fk];
      bfl[ni] = *(const short8*)&Bl[(wc * 64 + ni * 16 + fr) * LDST + fk];
    }
    #pragma unroll
    for (int mi = 0; mi < 4; mi++)
      #pragma unroll
      for (int ni = 0; ni < 4; ni++)
        acc[mi][ni] = __builtin_amdgcn_mfma_f32_16x16x32_bf16(afh[mi], bfh[ni], acc[mi][ni], 0, 0, 0);
    #pragma unroll
    for (int mi = 0; mi < 4; mi++)
      #pragma unroll
      for (int ni = 0; ni < 4; ni++)
        acc[mi][ni] = __builtin_amdgcn_mfma_f32_16x16x32_bf16(afh[mi], bfl[ni], acc[mi][ni], 0, 0, 0);
    #pragma unroll
    for (int mi = 0; mi < 4; mi++)
      #pragma unroll
      for (int ni = 0; ni < 4; ni++)
        acc[mi][ni] = __builtin_amdgcn_mfma_f32_16x16x32_bf16(afl[mi], bfh[ni], acc[mi][ni], 0, 0, 0);
  }

  const float* bias; float* fOut; bf16* hOut; bf16* lOut; int segStart, segW; float sscale; int sact;
  if (colBase >= start2)      { bias=bias2; fOut=f2; hOut=h2; lOut=l2; segStart=start2; segW=w2; sscale=sc2; sact=a2; }
  else if (colBase >= start1) { bias=bias1; fOut=f1; hOut=h1; lOut=l1; segStart=start1; segW=w1; sscale=sc1; sact=a1; }
  else                        { bias=bias0; fOut=f0; hOut=h0; lOut=l0; segStart=0;      segW=w0; sscale=sc0; sact=a0; }

  int cr = (lane >> 4) * 4;
  int cc = lane & 15;
  #pragma unroll
  for (int mi = 0; mi < 4; mi++) {
    #pragma unroll
    for (int ni = 0; ni < 4; ni++) {
      int col  = colBase + wc * 64 + ni * 16 + cc;
      int colL = col - segStart;
      float bv = bias[colL];
      #pragma unroll
      for (int j = 0; j < 4; j++) {
        int row = rowBase + wr * 64 + mi * 16 + cr + j;
        float val = (acc[mi][ni][j] + bv) * sscale;
        if (sact) val = 1.f / (1.f + expf(-val));
        if (resid && segStart == 0) val += resid[(size_t)row * segW + colL];
        size_t oidx = (size_t)row * segW + colL;
        if (fOut) fOut[oidx] = val;
        if (hOut) {
          bf16 h, l; split2(val, h, l);
          hOut[oidx] = h; lOut[oidx] = l;
        }
      }
    }
  }
}

// ---------------- causal conv over FEATURE axis (K=4) + SiLU ----------------
__global__ __launch_bounds__(256) void conv_kernel(const bf16* __restrict__ xth,
    const bf16* __restrict__ xtl, const float* __restrict__ cw,
    const float* __restrict__ cb, bf16* __restrict__ xch, bf16* __restrict__ xcl,
    int total)
{
  int idx = blockIdx.x * 256 + threadIdx.x;
  if (idx >= total) return;
  int p = idx & (Pq - 1);
  #define XT(i) (__bfloat162float(xth[i]) + __bfloat162float(xtl[i]))
  float acc = cb[0] + cw[3] * XT(idx);
  if (p >= 1) acc += cw[2] * XT(idx - 1);
  if (p >= 2) acc += cw[1] * XT(idx - 2);
  if (p >= 3) acc += cw[0] * XT(idx - 3);
  #undef XT
  float y = acc / (1.f + expf(-acc));   // silu
  bf16 h, l; split2(y, h, l);
  xch[idx] = h; xcl[idx] = l;
}

// ---------------- skinny i/f gate GEMM (N=8 each) + softcap ----------------
__global__ __launch_bounds__(256) void ifk_kernel(const bf16* __restrict__ xch,
    const bf16* __restrict__ xcl,
    const float* __restrict__ Wi, const float* __restrict__ bi,
    const float* __restrict__ Wf, const float* __restrict__ bf_,
    float* __restrict__ ip, float* __restrict__ fp)
{
  int row = blockIdx.x;              // b*S + t
  int lane = threadIdx.x & 63, wave = threadIdx.x >> 6;
  size_t rb = (size_t)row * Pq;
  for (int oi = wave; oi < 16; oi += 4) {
    int hh = oi & 7;
    const float* Wrow = (oi < 8) ? (Wi + (size_t)hh * Pq) : (Wf + (size_t)hh * Pq);
    float s = 0.f;
    for (int j = lane; j < Pq; j += 64)
      s += (__bfloat162float(xch[rb + j]) + __bfloat162float(xcl[rb + j])) * Wrow[j];
    #pragma unroll
    for (int mm = 32; mm > 0; mm >>= 1) s += __shfl_xor(s, mm, 64);
    if (lane == 0) {
      float val = s + ((oi < 8) ? bi[hh] : bf_[hh]);
      val = CAPq * tanhf(val / CAPq);
      if (oi < 8) ip[(size_t)row * Hq + hh] = val;
      else        fp[(size_t)row * Hq + hh] = val;
    }
  }
}

// ===== chunkwise-parallel mLSTM recurrence =====
// --- A: per-chunk scans + KV summary (grid: B*H*NC) ---
__global__ __launch_bounds__(256) void chunkA_kernel(const float* __restrict__ k,
    const float* __restrict__ v, const float* __restrict__ ip,
    const float* __restrict__ fp, float* __restrict__ bg,
    float* __restrict__ FcMc, float* __restrict__ kvg, float* __restrict__ ksumg)
{
  int blk = blockIdx.x;   // bh*NC + c
  int bh = blk >> 4, c = blk & 15;
  int b = bh >> 3, hh = bh & 7;
  int tid = threadIdx.x, lane = tid & 63, wave = tid >> 6;

  __shared__ float sK[64][64], sV[64][64], sW[64];

  size_t base = (size_t)b * Sq * 512 + (size_t)hh * 64 + (size_t)c * CLq * 512;
  #pragma unroll 4
  for (int i = 0; i < 16; i++) {
    int t = wave * 16 + i;
    sK[t][lane] = k[base + (size_t)t * 512 + lane];
    sV[t][lane] = v[base + (size_t)t * 512 + lane];
  }
  if (tid < 64) {
    size_t ifb = ((size_t)b * Sq + c * CLq + tid) * Hq + hh;
    float fv = fp[ifb], iv = ip[ifb];
    float cf = fv;                       // inclusive sum scan of f
    #pragma unroll
    for (int off = 1; off < 64; off <<= 1) {
      float t2 = __shfl_up(cf, off, 64);
      if (lane >= off) cf += t2;
    }
    float bs = iv - cf;
    float mx = bs;                       // inclusive max scan
    #pragma unroll
    for (int off = 1; off < 64; off <<= 1) {
      float t2 = __shfl_up(mx, off, 64);
      if (lane >= off) mx = fmaxf(mx, t2);
    }
    float Mc = __shfl(mx, 63, 64);
    bg[(size_t)blk * 64 + tid] = bs;
    sW[tid] = expf(bs - Mc);
    if (tid == 63) { FcMc[blk*2] = cf; FcMc[blk*2+1] = Mc; }
  }
  __syncthreads();
  float acc[16];
  #pragma unroll
  for (int j = 0; j < 16; j++) acc[j] = 0.f;
  for (int s = 0; s < 64; s++) {
    float wv = sW[s] * sV[s][lane];
    #pragma unroll
    for (int j = 0; j < 16; j++) acc[j] += wv * sK[s][wave*16+j];
  }
  float* kvp = kvg + (size_t)blk * 4096 + lane * 64 + wave * 16;
  #pragma unroll
  for (int j = 0; j < 16; j++) kvp[j] = acc[j];
  if (tid < 64) {
    float a = 0.f;
    for (int s = 0; s < 64; s++) a += sW[s] * sK[s][tid];
    ksumg[(size_t)blk * 64 + tid] = a;
  }
}

// --- B: boundary-state propagation, 16 sequential chunk steps (grid: B*H) ---
__global__ __launch_bounds__(256) void chunkB_kernel(const float* __restrict__ kvg,
    const float* __restrict__ ksumg, const float* __restrict__ FcMc,
    float* __restrict__ boundC, float* __restrict__ boundN, float* __restrict__ boundM)
{
  int bh = blockIdx.x;
  int tid = threadIdx.x, lane = tid & 63, wave = tid >> 6;
  float C[16];
  #pragma unroll
  for (int j = 0; j < 16; j++) C[j] = 0.f;
  float ne = 1.0f, m = 0.f;              // n0 = ones, m0 = 0
  for (int c = 0; c < NCq; c++) {
    size_t blk = (size_t)bh * NCq + c;
    float* bC = boundC + blk * 4096 + lane * 64 + wave * 16;
    #pragma unroll
    for (int j = 0; j < 16; j++) bC[j] = C[j];
    if (wave == 0) boundN[blk * 64 + lane] = ne;
    if (tid == 0)  boundM[blk] = m;
    float Fc = FcMc[blk * 2], Mc = FcMc[blk * 2 + 1];
    float mm = fmaxf(m, Mc);
    float a1 = expf(m - mm), a2 = expf(Mc - mm);
    const float* kv = kvg + blk * 4096 + lane * 64 + wave * 16;
    #pragma unroll
    for (int j = 0; j < 16; j++) C[j] = a1 * C[j] + a2 * kv[j];
    ne = a1 * ne + a2 * ksumg[blk * 64 + lane];
    m = Fc + mm;
  }
}

// --- C: intra-chunk parallel attention (grid: B*H*NC). q/hs may ALIAS. ---
__global__ __launch_bounds__(256) void chunkC_kernel(const float* q,
    const float* __restrict__ k, const float* __restrict__ v,
    const float* __restrict__ bg, const float* __restrict__ boundC,
    const float* __restrict__ boundN, const float* __restrict__ boundM,
    float* hs)
{
  int blk = blockIdx.x;   // bh*NC + c
  int bh = blk >> 4, c = blk & 15;
  int b = bh >> 3, hh = bh & 7;
  int tid = threadIdx.x, lane = tid & 63, wave = tid >> 6;

  __shared__ float sQ[64][65], sKV[64][65], sS[64][65];
  __shared__ float sB[64], sMr[64], sNin[64];

  size_t base = (size_t)b * Sq * 512 + (size_t)hh * 64 + (size_t)c * CLq * 512;
  #pragma unroll 4
  for (int i = 0; i < 16; i++) {
    int t = wave * 16 + i;
    sQ[t][lane]  = q[base + (size_t)t * 512 + lane];
    sKV[t][lane] = k[base + (size_t)t * 512 + lane];
  }
  float m_in = boundM[blk];
  if (tid < 64) {
    float bs = bg[(size_t)blk * 64 + tid];
    float mx = bs;
    #pragma unroll
    for (int off = 1; off < 64; off <<= 1) {
      float t2 = __shfl_up(mx, off, 64);
      if (lane >= off) mx = fmaxf(mx, t2);
    }
    sB[tid]   = bs;
    sMr[tid]  = fmaxf(m_in, mx);
    sNin[tid] = boundN[(size_t)blk * 64 + tid];
  }
  __syncthreads();

  {
    int t = lane;
    float acc[16];
    #pragma unroll
    for (int j = 0; j < 16; j++) acc[j] = 0.f;
    for (int d = 0; d < 64; d++) {
      float qv = sQ[t][d];
      #pragma unroll
      for (int j = 0; j < 16; j++) acc[j] += qv * sKV[wave*16+j][d];
    }
    float Mr = sMr[t];
    #pragma unroll
    for (int j = 0; j < 16; j++) {
      int s = wave * 16 + j;
      float w = (s <= t) ? expf(sB[s] - Mr) : 0.f;
      sS[t][s] = w * acc[j];
    }
  }
  __syncthreads();
  #pragma unroll 4
  for (int i = 0; i < 16; i++) {       // restage v over k
    int t = wave * 16 + i;
    sKV[t][lane] = v[base + (size_t)t * 512 + lane];
  }
  __syncthreads();

  {
    int t = lane;
    float Mr = sMr[t];
    float bfac = expf(m_in - Mr);
    float den = 0.f;
    for (int d = 0; d < 64; d++) den += sNin[d] * sQ[t][d];
    den *= bfac;
    float num[16];
    #pragma unroll
    for (int j = 0; j < 16; j++) num[j] = 0.f;
    const float* Crow = boundC + (size_t)blk * 4096;
    for (int e = 0; e < 64; e++) {
      float qv = sQ[t][e];
      #pragma unroll
      for (int j = 0; j < 16; j++)
        num[j] += Crow[(size_t)(wave*16+j) * 64 + e] * qv;
    }
    #pragma unroll
    for (int j = 0; j < 16; j++) num[j] *= bfac;
    for (int s = 0; s < 64; s++) {
      float ws = sS[t][s];
      den += ws;
      #pragma unroll
      for (int j = 0; j < 16; j++) num[j] += ws * sKV[s][wave*16+j];
    }
    den = fmaxf(den, 1.0f);
    float o[16];
    #pragma unroll
    for (int j = 0; j < 16; j++) o[j] = num[j] / den;
    float* hp = hs + base + (size_t)t * 512 + wave * 16;
    #pragma unroll
    for (int j4 = 0; j4 < 4; j4++)
      ((float4*)hp)[j4] = ((float4*)o)[j4];
  }
}

// ------ epilogue: h=o*hs; per-head LN; (hn+skip)*silu(r) -> hi/lo bf16 ------
__global__ __launch_bounds__(256) void epi_kernel(const float* __restrict__ hsv,
    const float* __restrict__ ov, const float* __restrict__ xs,
    const float* __restrict__ rt, const float* __restrict__ mg,
    const float* __restrict__ mb, bf16* __restrict__ pdh, bf16* __restrict__ pdl)
{
  int tid = threadIdx.x;
  int lane = tid & 63, wave = tid >> 6;
  size_t row = (size_t)blockIdx.x * 4 + wave;   // over B*S*H
  int hh = (int)(row & 7);
  size_t idx = row * 64 + lane;
  float hv = ov[idx] * hsv[idx];
  float s = hv, s2 = hv * hv;
  #pragma unroll
  for (int mm = 32; mm > 0; mm >>= 1) { s += __shfl_xor(s, mm, 64); s2 += __shfl_xor(s2, mm, 64); }
  float mu  = s * (1.f / 64.f);
  float var = s2 * (1.f / 64.f) - mu * mu;
  float r = rsqrtf(var + EPSq);
  float hn = (hv - mu) * r * mg[hh * 64 + lane] + mb[hh * 64 + lane];
  float rv = rt[idx];
  float y = (hn + xs[idx]) * (rv / (1.f + expf(-rv)));
  bf16 h, l; split2(y, h, l);
  pdh[idx] = h; pdl[idx] = l;
}

extern "C" void kernel_launch(void* const* d_in, const int* in_sizes, int n_in,
                              void* d_out, int out_size, void* d_ws, size_t ws_size,
                              hipStream_t stream)
{
  const float* x      = (const float*)d_in[0];
  const float* ln_g   = (const float*)d_in[1];
  const float* ln_b   = (const float*)d_in[2];
  const float* mh_g   = (const float*)d_in[3];
  const float* mh_b   = (const float*)d_in[4];
  const float* W_up_l = (const float*)d_in[5];
  const float* b_up_l = (const float*)d_in[6];
  const float* W_up_r = (const float*)d_in[7];
  const float* b_up_r = (const float*)d_in[8];
  const float* W_down = (const float*)d_in[9];
  const float* b_down = (const float*)d_in[10];
  const float* conv_w = (const float*)d_in[11];
  const float* conv_b = (const float*)d_in[12];
  const float* W_skip = (const float*)d_in[13];
  const float* b_skip = (const float*)d_in[14];
  const float* W_i    = (const float*)d_in[15];
  const float* b_i    = (const float*)d_in[16];
  const float* W_f    = (const float*)d_in[17];
  const float* b_f    = (const float*)d_in[18];
  const float* W_o    = (const float*)d_in[19];
  const float* b_o    = (const float*)d_in[20];
  const float* W_q    = (const float*)d_in[21];
  const float* b_q    = (const float*)d_in[22];
  const float* W_k    = (const float*)d_in[23];
  const float* b_k    = (const float*)d_in[24];
  const float* W_v    = (const float*)d_in[25];
  const float* b_v    = (const float*)d_in[26];
  float* out = (float*)d_out;

  const size_t MB = 1u << 20;
  if (ws_size < 193 * MB) return;

  char* base = (char*)d_ws;
  bf16* whi = (bf16*)base;             // 0..16 MB
  bf16* wlo = (bf16*)(base + 16*MB);   // 16..32 MB
  bf16* xnh = (bf16*)(base + 32*MB);
  bf16* xnl = (bf16*)(base + 48*MB);
  bf16* xth = (bf16*)(base + 64*MB);
  bf16* xtl = (bf16*)(base + 96*MB);
  bf16* xch = (bf16*)(base + 128*MB);
  bf16* xcl = (bf16*)(base + 160*MB);
  // reuse of dead regions:
  float* vb  = (float*)(base + 32*MB); // xn region
  float* ob  = (float*)(base + 48*MB);
  float* xs  = (float*)(base + 64*MB); // xt region
  float* qb  = (float*)(base + 80*MB);
  float* kb  = (float*)(base + 96*MB);
  bf16*  pdh = (bf16*)(base + 112*MB);
  bf16*  pdl = (bf16*)(base + 120*MB);
  // chunkwise-recurrence buffers in dead xc region (after ifk):
  float* kvg    = (float*)(base + 128*MB);            // 16 MB
  float* boundC = (float*)(base + 144*MB);            // 16 MB
  float* bg     = (float*)(base + 160*MB);            // 256 KB
  float* ksumg  = (float*)(base + 160*MB + 256*1024); // 256 KB
  float* boundN = (float*)(base + 160*MB + 512*1024); // 256 KB
  float* FcMc   = (float*)(base + 160*MB + 768*1024); // 8 KB
  float* boundM = (float*)(base + 160*MB + 776*1024); // 4 KB
  float* ip  = (float*)(base + 192*MB);
  float* fpb = (float*)(base + 192*MB + 256*1024);
  float* rt  = out;                    // d_out scratch; down GEMM overwrites
  float* hsb = qb;                     // hs aliases qb (chunkC stages q first)

  const int Mrows = Bq * Sq;   // 8192
  const int BIG = 1 << 30;

  cvtw_all<<<dim3(8192), dim3(256), 0, stream>>>(
      W_up_l, W_up_r, W_v, W_o, W_skip, W_q, W_k, W_down, whi, wlo);

  ln_kernel<<<dim3(Mrows), dim3(256), 0, stream>>>(x, ln_g, ln_b, xnh, xnl);

  gemm_x3<<<dim3(20, 64), dim3(256), 0, stream>>>(
      xnh, xnl, whi, wlo, 1024, 2048, BIG, nullptr,
      b_up_l, nullptr, xth, xtl, 2048, 1.f, 0,
      b_up_r, rt, nullptr, nullptr, 512, 1.f, 0,
      nullptr, nullptr, nullptr, nullptr, 1, 1.f, 0);

  gemm_x3<<<dim3(8, 64), dim3(256), 0, stream>>>(
      xth, xtl, whi + 2621440, wlo + 2621440, 2048, 512, BIG, nullptr,
      b_v, vb, nullptr, nullptr, 512, 1.f, 0,
      b_o, ob, nullptr, nullptr, 512, 1.f, 1,
      nullptr, nullptr, nullptr, nullptr, 1, 1.f, 0);

  int convTotal = Mrows * Pq;
  conv_kernel<<<dim3(convTotal / 256), dim3(256), 0, stream>>>(
      xth, xtl, conv_w, conv_b, xch, xcl, convTotal);

  gemm_x3<<<dim3(12, 64), dim3(256), 0, stream>>>(
      xch, xcl, whi + 4718592, wlo + 4718592, 2048, 512, 1024, nullptr,
      b_skip, xs, nullptr, nullptr, 512, 1.f, 0,
      b_q, qb, nullptr, nullptr, 512, 1.f, 0,
      b_k, kb, nullptr, nullptr, 512, 0.125f, 0);

  ifk_kernel<<<dim3(Mrows), dim3(256), 0, stream>>>(
      xch, xcl, W_i, b_i, W_f, b_f, ip, fpb);
  // xc dead from here; chunk buffers live in its region

  chunkA_kernel<<<dim3(Bq * Hq * NCq), dim3(256), 0, stream>>>(
      kb, vb, ip, fpb, bg, FcMc, kvg, ksumg);
  chunkB_kernel<<<dim3(Bq * Hq), dim3(256), 0, stream>>>(
      kvg, ksumg, FcMc, boundC, boundN, boundM);
  chunkC_kernel<<<dim3(Bq * Hq * NCq), dim3(256), 0, stream>>>(
      qb, kb, vb, bg, boundC, boundN, boundM, hsb);

  epi_kernel<<<dim3(Mrows * Hq / 4), dim3(256), 0, stream>>>(
      hsb, ob, xs, rt, mh_g, mh_b, pdh, pdl);

  gemm_x3<<<dim3(8, 64), dim3(256), 0, stream>>>(
      pdh, pdl, whi + 7864320, wlo + 7864320, 512, BIG, BIG, x,
      b_down, out, nullptr, nullptr, 1024, 1.f, 0,
      nullptr, nullptr, nullptr, nullptr, 1, 1.f, 0,
      nullptr, nullptr, nullptr, nullptr, 1, 1.f, 0);
}